// Round 4
// baseline (207.457 us; speedup 1.0000x reference)
//
#include <hip/hip_runtime.h>
#include <stdint.h>
#include <math.h>

typedef unsigned long long u64;
typedef uint32_t u32;

#define BATCH   262144
#define DIM     120
#define NBLK1   2048      // K1/K2: 128 rows per block
#define NPART   4096      // partial slots per column (2 halves * 2048 blocks)

// ---------------- workspace layout (bytes) ----------------
#define WS_XBITS   0              // u64[BATCH*4]            8,388,608
#define WS_WBITS   8388608        // u64[128*4]                  4,096
#define WS_LWPL    8392704        // u64[8] lin_w bit-planes        64
#define WS_THRP    8392768        // u32[128] packed thresholds    512
#define WS_HS      8393280        // u32[120*4096]           1,966,080
#define WS_HS2     10359360       // u32[120*4096]           1,966,080
#define WS_SS      12325440       // f32[120*4096]           1,966,080
#define WS_SS2     14291520       // f32[120*4096]           1,966,080
#define WS_BN2C    16257600       // f32[256]  (c1q[j], c0[128+j])
#define WS_OQ      16258624       // u32[BATCH]              1,048,576
#define WS_OACC    17307200       // u32 oS[2]; pad; u64 oS2[2]@+16
#define WS_TOTAL   17307264

// Pack conv_w via ballots (coalesced) in the same permuted bit order as the
// x packing: col c -> word (c&1), bit (c>>1). Zero the pad columns 120-127,
// build lin_w binarize BIT-PLANES (lwpl[c*4+g*2+t], t:0=LL,1=LH, bit l of
// group g = column g*64+l), zero pad thresholds, zero k3 accumulators.
__global__ __launch_bounds__(256) void kw_pack(
        const float* __restrict__ w, const float* __restrict__ lw,
        u64* __restrict__ wbits, u64* __restrict__ lwpl,
        u32* __restrict__ thrp, u32* __restrict__ oaccz) {
    int tid = threadIdx.x, lane = tid & 63, wv = tid >> 6;
    if (tid < 8) oaccz[tid] = 0;
    for (int j = wv; j < DIM; j += 4) {
        float2 v = make_float2(-1.f, -1.f);
        if (lane < 60) v = *(const float2*)(w + (size_t)j * DIM + lane * 2);
        u64 pe = __ballot(v.x > 0.f);
        u64 po = __ballot(v.y > 0.f);
        u64 ze = __ballot(v.x == 0.f);
        u64 zo = __ballot(v.y == 0.f);
        if (lane == 0) {
            wbits[j*4+0] = pe; wbits[j*4+1] = po;
            wbits[j*4+2] = ze; wbits[j*4+3] = zo;
        }
    }
    if (tid >= 120 && tid < 128) {        // zero pad columns
        wbits[tid*4+0] = 0; wbits[tid*4+1] = 0;
        wbits[tid*4+2] = 0; wbits[tid*4+3] = 0;
        thrp[tid] = 0;
    }
    if (wv < 2) {                         // lin_w bit-planes, group wv
        int col = wv * 64 + lane;
        float w0 = col < DIM ? lw[col] : -1.f;
        float w1 = col < DIM ? lw[DIM + col] : -1.f;
        u32 l0 = w0 > 0.f ? 2u : (w0 == 0.f ? 1u : 0u);
        u32 l1 = w1 > 0.f ? 2u : (w1 == 0.f ? 1u : 0u);
        u64 ll0 = __ballot(l0 & 1), lh0 = __ballot(l0 >> 1);
        u64 ll1 = __ballot(l1 & 1), lh1 = __ballot(l1 >> 1);
        if (lane == 0) {
            lwpl[0 + wv*2 + 0] = ll0;  lwpl[0 + wv*2 + 1] = lh0;
            lwpl[4 + wv*2 + 0] = ll1;  lwpl[4 + wv*2 + 1] = lh1;
        }
    }
}

__device__ __forceinline__ u32 hq_from_bits(u64 p0, u64 p1, u64 z0, u64 z1,
                                            u64 q0, u64 q1, u64 y0, u64 y1,
                                            bool hasY, bool hasZ) {
    u32 hq = (u32)(__popcll(p0 & q0) + __popcll(p1 & q1)) << 2;
    if (hasY)
        hq += 2u * (u32)(__popcll(p0 & y0) + __popcll(p1 & y1))
            + (u32)(__popcll(z0 & y0) + __popcll(z1 & y1));
    if (hasZ)
        hq += 2u * (u32)(__popcll(z0 & q0) + __popcll(z1 & q1));
    return hq;   // == 4 * h, exact integer in [0, 480]
}

// K1: pack x into bits (ballot), store bits to global, compute integer
// per-column sums of hq and hq^2 (exact, deterministic).
__global__ __launch_bounds__(256) void k1_pack_hstats(
        const float* __restrict__ x, const u64* __restrict__ wbits,
        u64* __restrict__ xbits, u32* __restrict__ hS, u32* __restrict__ hS2) {
    __shared__ u64 lb[128][4];
    int tid = threadIdx.x, lane = tid & 63, wave = tid >> 6;
    size_t rowbase = (size_t)blockIdx.x * 128;

    for (int rr = 0; rr < 32; ++rr) {
        int r = wave * 32 + rr;
        float2 v = make_float2(-1.f, -1.f);
        if (lane < 60) v = *(const float2*)(x + (rowbase + r) * (size_t)DIM + lane * 2);
        u64 pe = __ballot(v.x > 0.f);
        u64 po = __ballot(v.y > 0.f);
        u64 ze = __ballot(v.x == 0.f);
        u64 zo = __ballot(v.y == 0.f);
        if (lane == 0) { lb[r][0] = pe; lb[r][1] = po; lb[r][2] = ze; lb[r][3] = zo; }
    }
    __syncthreads();
    ((ulonglong2*)(xbits + (size_t)blockIdx.x * 512))[tid] =
        ((const ulonglong2*)&lb[0][0])[tid];

    int j = tid & 127, half = tid >> 7;
    if (j < DIM) {
        u64 q0 = wbits[j*4+0], q1 = wbits[j*4+1], y0 = wbits[j*4+2], y1 = wbits[j*4+3];
        bool hasY = (y0 | y1) != 0;
        u32 S = 0, S2 = 0;
        int r0 = half * 64;
        for (int r = r0; r < r0 + 64; ++r) {
            u64 z0 = lb[r][2], z1 = lb[r][3];
            u32 hq = hq_from_bits(lb[r][0], lb[r][1], z0, z1,
                                  q0, q1, y0, y1, hasY, (z0 | z1) != 0);
            S += hq; S2 += hq * hq;
        }
        int pidx = j * NPART + blockIdx.x * 2 + half;
        hS[pidx] = S; hS2[pidx] = S2;
    }
}

// R1: reduce integer h-stats -> fold BN2 into  z = fma(hq, c1q, c0)
__global__ __launch_bounds__(256) void r1_hreduce(
        const u32* __restrict__ hS, const u32* __restrict__ hS2,
        const float* __restrict__ g2, const float* __restrict__ b2,
        float* __restrict__ bn2c) {
    int j = blockIdx.x, tid = threadIdx.x;
    u32 s = 0; u64 s2 = 0;
    for (int k = tid; k < NPART; k += 256) { s += hS[j*NPART+k]; s2 += (u64)hS2[j*NPART+k]; }
    for (int off = 32; off; off >>= 1) { s += __shfl_down(s, off, 64); s2 += __shfl_down(s2, off, 64); }
    __shared__ u32 as_[4]; __shared__ u64 as2_[4];
    int lane = tid & 63, wave = tid >> 6;
    if (lane == 0) { as_[wave] = s; as2_[wave] = s2; }
    __syncthreads();
    if (tid == 0) {
        u32 S = as_[0] + as_[1] + as_[2] + as_[3];
        u64 S2 = as2_[0] + as2_[1] + as2_[2] + as2_[3];
        double m2 = (double)S * 0.25 / (double)BATCH;
        double e2 = (double)S2 * 0.0625 / (double)BATCH;
        double v2 = e2 - m2 * m2;
        float rs = (float)(1.0 / sqrt(v2 + 1e-5));
        float c1 = rs * g2[j];
        float c0 = fmaf(-(float)m2, c1, b2[j]);
        bn2c[j]       = c1 * 0.25f;   // pre-scaled for hq (=4h)
        bn2c[128 + j] = c0;
    }
}

// K2: stage bits in LDS, recompute hq, softsign stats (dual f32 accumulators)
__global__ __launch_bounds__(256) void k2_sstats(
        const u64* __restrict__ xbits, const u64* __restrict__ wbits,
        const float* __restrict__ bn2c,
        float* __restrict__ sS, float* __restrict__ sS2) {
    __shared__ u64 lb[128][4];
    int tid = threadIdx.x;
    ((ulonglong2*)&lb[0][0])[tid] =
        ((const ulonglong2*)(xbits + (size_t)blockIdx.x * 512))[tid];
    __syncthreads();
    int j = tid & 127, half = tid >> 7;
    if (j >= DIM) return;
    u64 q0 = wbits[j*4+0], q1 = wbits[j*4+1], y0 = wbits[j*4+2], y1 = wbits[j*4+3];
    bool hasY = (y0 | y1) != 0;
    float c1q = bn2c[j], c0 = bn2c[128 + j];
    float SsA = 0.f, Ss2A = 0.f, SsB = 0.f, Ss2B = 0.f;
    int r0 = half * 64;
    for (int r = r0; r < r0 + 64; r += 2) {
        u64 z0 = lb[r][2], z1 = lb[r][3];
        u32 hqa = hq_from_bits(lb[r][0], lb[r][1], z0, z1,
                               q0, q1, y0, y1, hasY, (z0 | z1) != 0);
        u64 w0 = lb[r+1][2], w1 = lb[r+1][3];
        u32 hqb = hq_from_bits(lb[r+1][0], lb[r+1][1], w0, w1,
                               q0, q1, y0, y1, hasY, (w0 | w1) != 0);
        float za = fmaf((float)hqa, c1q, c0);
        float sa = za * __builtin_amdgcn_rcpf(1.f + fabsf(za));
        SsA += sa; Ss2A = fmaf(sa, sa, Ss2A);
        float zb = fmaf((float)hqb, c1q, c0);
        float sb = zb * __builtin_amdgcn_rcpf(1.f + fabsf(zb));
        SsB += sb; Ss2B = fmaf(sb, sb, Ss2B);
    }
    int pidx = j * NPART + blockIdx.x * 2 + half;
    sS[pidx] = SsA + SsB; sS2[pidx] = Ss2A + Ss2B;
}

// R2: reduce softsign stats (f64), fold BN1, derive the two integer
// thresholds per column (h1(hq) monotone in hq), pack as A|B<<16|dec<<31.
__global__ __launch_bounds__(256) void r2_sreduce(
        const float* __restrict__ sS, const float* __restrict__ sS2,
        const float* __restrict__ g1, const float* __restrict__ b1,
        const float* __restrict__ bn2c, u32* __restrict__ thrp) {
    int j = blockIdx.x, tid = threadIdx.x;
    double s = 0.0, s2 = 0.0;
    for (int k = tid; k < NPART; k += 256) { s += (double)sS[j*NPART+k]; s2 += (double)sS2[j*NPART+k]; }
    for (int off = 32; off; off >>= 1) { s += __shfl_down(s, off, 64); s2 += __shfl_down(s2, off, 64); }
    __shared__ double ds_[4], ds2_[4];
    __shared__ float sd1, sd0;
    __shared__ u32 cnt[3];
    __shared__ u32 sfirst, slast;
    int lane = tid & 63, wave = tid >> 6;
    if (lane == 0) { ds_[wave] = s; ds2_[wave] = s2; }
    if (tid < 3) cnt[tid] = 0;
    __syncthreads();
    if (tid == 0) {
        double S = ds_[0] + ds_[1] + ds_[2] + ds_[3];
        double S2 = ds2_[0] + ds2_[1] + ds2_[2] + ds2_[3];
        double m1 = S / (double)BATCH;
        double v1 = S2 / (double)BATCH - m1 * m1;
        float rs = (float)(1.0 / sqrt(v1 + 1e-5));
        float d1 = rs * g1[j];
        float d0 = fmaf(-(float)m1, d1, b1[j]);
        sd1 = d1; sd0 = d0;
    }
    __syncthreads();
    float c1q = bn2c[j], c0 = bn2c[128 + j];
    float d1 = sd1, d0 = sd0;
    for (int hq = tid; hq < 481; hq += 256) {
        float z = fmaf((float)hq, c1q, c0);
        float sv = z * __builtin_amdgcn_rcpf(1.f + fabsf(z));
        float h1 = fmaf(sv, d1, d0);
        u32 hb2 = h1 > 0.f ? 2u : (h1 == 0.f ? 1u : 0u);
        atomicAdd(&cnt[hb2], 1u);
        if (hq == 0)   sfirst = hb2;
        if (hq == 480) slast  = hb2;
    }
    __syncthreads();
    if (tid == 0) {
        u32 n0 = cnt[0], n1 = cnt[1], n2 = cnt[2];
        u32 dec = (slast < sfirst) ? 1u : 0u;
        u32 A = dec ? n2 : n0;
        u32 B = A + n1;
        thrp[j] = A | (B << 16) | (dec << 31);
    }
}

// K3: column-parallel. Wave w: column group g=w&1 (lane -> col g*64+lane),
// row half rh=w>>1. Per-column constants loaded ONCE into registers; rows
// streamed from LDS (same-address broadcast). hb2 repacked row-major via
// ballot; 120x2 matvec done per-row with 16 popcounts against lin_w planes.
__global__ __launch_bounds__(256) void k3_out(
        const u64* __restrict__ xbits, const u64* __restrict__ wbits,
        const u32* __restrict__ thrp, const u64* __restrict__ lwpl,
        u32* __restrict__ oqbuf, u32* __restrict__ oS, u64* __restrict__ oS2) {
    __shared__ u64 lb[128][4];
    __shared__ u64 pk[128][4];      // [row][g*2 + (0=lo,1=hi)]
    int tid = threadIdx.x, lane = tid & 63, wv = tid >> 6;
    ((ulonglong2*)&lb[0][0])[tid] =
        ((const ulonglong2*)(xbits + (size_t)blockIdx.x * 512))[tid];
    __syncthreads();

    // ---- column phase ----
    int g = wv & 1, rh = wv >> 1;
    int col = g * 64 + lane;
    u64 q0 = wbits[col*4+0], q1 = wbits[col*4+1];
    u64 y0 = wbits[col*4+2], y1 = wbits[col*4+3];
    u32 t = thrp[col];
    u32 A = t & 0xffffu, B = (t >> 16) & 0x7fffu;
    bool dec = (t >> 31) != 0;
    bool anyY = __ballot((y0 | y1) != 0) != 0;   // wave-uniform
    int r0 = rh * 64;
    for (int r = r0; r < r0 + 64; ++r) {
        u64 p0 = lb[r][0], p1 = lb[r][1], z0 = lb[r][2], z1 = lb[r][3];
        u32 hq = (u32)(__popcll(p0 & q0) + __popcll(p1 & q1)) << 2;
        if (anyY) {
            hq += 2u * (u32)(__popcll(p0 & y0) + __popcll(p1 & y1));
            if (z0 | z1) hq += (u32)(__popcll(z0 & y0) + __popcll(z1 & y1));
        }
        if (z0 | z1)       // wave-uniform (whole wave shares row r)
            hq += 2u * (u32)(__popcll(z0 & q0) + __popcll(z1 & q1));
        u32 hb2 = dec ? (u32)(hq < A) + (u32)(hq < B)
                      : (u32)(hq >= A) + (u32)(hq >= B);
        u64 blo = __ballot(hb2 & 1);
        u64 bhi = __ballot(hb2 >> 1);
        if (lane == 0) { pk[r][g*2+0] = blo; pk[r][g*2+1] = bhi; }
    }
    __syncthreads();

    // ---- row phase: oq = sum_j hb2[j]*lw[c][j] via bit-plane popcounts ----
    u32 o0 = 0, o1 = 0;
    if (tid < 128) {
        u64 lo0 = pk[tid][0], hi0 = pk[tid][1], lo1 = pk[tid][2], hi1 = pk[tid][3];
        u64 a0 = lwpl[0], a1 = lwpl[1], a2 = lwpl[2], a3 = lwpl[3];
        u64 b0 = lwpl[4], b1 = lwpl[5], b2 = lwpl[6], b3 = lwpl[7];
        o0 = 4u*(u32)__popcll(hi0 & a1) + 2u*(u32)__popcll(hi0 & a0)
           + 2u*(u32)__popcll(lo0 & a1) +     (u32)__popcll(lo0 & a0)
           + 4u*(u32)__popcll(hi1 & a3) + 2u*(u32)__popcll(hi1 & a2)
           + 2u*(u32)__popcll(lo1 & a3) +     (u32)__popcll(lo1 & a2);
        o1 = 4u*(u32)__popcll(hi0 & b1) + 2u*(u32)__popcll(hi0 & b0)
           + 2u*(u32)__popcll(lo0 & b1) +     (u32)__popcll(lo0 & b0)
           + 4u*(u32)__popcll(hi1 & b3) + 2u*(u32)__popcll(hi1 & b2)
           + 2u*(u32)__popcll(lo1 & b3) +     (u32)__popcll(lo1 & b2);
        oqbuf[(size_t)blockIdx.x * 128 + tid] = o0 | (o1 << 16);
    }
    u32 a = o0, b = o1, c2 = o0 * o0, d2 = o1 * o1;
    for (int off = 32; off; off >>= 1) {
        a += __shfl_down(a, off, 64);  b += __shfl_down(b, off, 64);
        c2 += __shfl_down(c2, off, 64); d2 += __shfl_down(d2, off, 64);
    }
    __shared__ u32 r0_[4], r1_[4], r2_[4], r3_[4];
    if (lane == 0) { r0_[wv] = a; r1_[wv] = b; r2_[wv] = c2; r3_[wv] = d2; }
    __syncthreads();
    if (tid == 0) {
        atomicAdd(&oS[0], r0_[0] + r0_[1] + r0_[2] + r0_[3]);
        atomicAdd(&oS[1], r1_[0] + r1_[1] + r1_[2] + r1_[3]);
        atomicAdd(&oS2[0], (u64)(r2_[0] + r2_[1] + r2_[2] + r2_[3]));
        atomicAdd(&oS2[1], (u64)(r3_[0] + r3_[1] + r3_[2] + r3_[3]));
    }
}

// K4: finalize output BN constants in-block (lin_b cancels through the
// no-affine BN), then normalize + 2-class log_softmax.
__global__ __launch_bounds__(256) void k4_final(
        const u32* __restrict__ oqbuf, const u32* __restrict__ oS,
        const u64* __restrict__ oS2, float* __restrict__ out) {
    __shared__ float sfin[4];
    int tid = threadIdx.x;
    if (tid < 2) {
        double a  = (double)oS[tid] * 0.25 / (double)BATCH;
        double e2 = (double)oS2[tid] * 0.0625 / (double)BATCH;
        double vo = e2 - a * a;
        sfin[tid]     = (float)a;
        sfin[2 + tid] = (float)(1.0 / sqrt(vo + 1e-5));
    }
    __syncthreads();
    size_t row = (size_t)blockIdx.x * 256 + tid;
    u32 v = oqbuf[row];
    float o0 = ((float)(v & 0xffffu) * 0.25f - sfin[0]) * sfin[2];
    float o1 = ((float)(v >> 16)     * 0.25f - sfin[1]) * sfin[3];
    float m = fmaxf(o0, o1);
    float l0 = o0 - m, l1 = o1 - m;
    float ls = logf(expf(l0) + expf(l1));
    ((float2*)out)[row] = make_float2(l0 - ls, l1 - ls);
}

extern "C" void kernel_launch(void* const* d_in, const int* in_sizes, int n_in,
                              void* d_out, int out_size, void* d_ws, size_t ws_size,
                              hipStream_t stream) {
    const float* x  = (const float*)d_in[0];
    const float* cw = (const float*)d_in[1];
    const float* g2 = (const float*)d_in[2];
    const float* b2 = (const float*)d_in[3];
    const float* g1 = (const float*)d_in[4];
    const float* b1 = (const float*)d_in[5];
    const float* lw = (const float*)d_in[6];
    // d_in[7] (lin_b) cancels through the final no-affine batchnorm
    float* out = (float*)d_out;
    if (ws_size < (size_t)WS_TOTAL) return;   // fail loudly via poisoned d_out

    char* ws = (char*)d_ws;
    u64* xbits = (u64*)(ws + WS_XBITS);
    u64* wbits = (u64*)(ws + WS_WBITS);
    u64* lwpl  = (u64*)(ws + WS_LWPL);
    u32* thrp  = (u32*)(ws + WS_THRP);
    u32* hS    = (u32*)(ws + WS_HS);
    u32* hS2   = (u32*)(ws + WS_HS2);
    float* sS  = (float*)(ws + WS_SS);
    float* sS2 = (float*)(ws + WS_SS2);
    float* bn2c = (float*)(ws + WS_BN2C);
    u32* oqbuf = (u32*)(ws + WS_OQ);
    u32* oS    = (u32*)(ws + WS_OACC);
    u64* oS2   = (u64*)(ws + WS_OACC + 16);

    kw_pack       <<<1, 256, 0, stream>>>(cw, lw, wbits, lwpl, thrp, oS);
    k1_pack_hstats<<<NBLK1, 256, 0, stream>>>(x, wbits, xbits, hS, hS2);
    r1_hreduce    <<<DIM, 256, 0, stream>>>(hS, hS2, g2, b2, bn2c);
    k2_sstats     <<<NBLK1, 256, 0, stream>>>(xbits, wbits, bn2c, sS, sS2);
    r2_sreduce    <<<DIM, 256, 0, stream>>>(sS, sS2, g1, b1, bn2c, thrp);
    k3_out        <<<BATCH/128, 256, 0, stream>>>(xbits, wbits, thrp, lwpl, oqbuf, oS, oS2);
    k4_final      <<<BATCH/256, 256, 0, stream>>>(oqbuf, oS, oS2, out);
}

// Round 5
// 155.083 us; speedup vs baseline: 1.3377x; 1.3377x over previous
//
#include <hip/hip_runtime.h>
#include <stdint.h>
#include <math.h>

typedef unsigned long long u64;
typedef uint32_t u32;

#define BATCH   262144
#define DIM     120
#define NBLK1   2048      // K1/K2: 128 rows per block
#define NPART   4096      // partial slots per column (2 halves * 2048 blocks)

// ---------------- workspace layout (bytes) ----------------
#define WS_XBITS   0              // u64[BATCH*4]            8,388,608
#define WS_WBITS   8388608        // u64[128*4]                  4,096
#define WS_LWQ     8392704        // u32[128]                      512
#define WS_META    8393216        // u32[256] (2 per col)        1,024
#define WS_HS      8394240        // u32[120*4096]           1,966,080
#define WS_HS2     10360320      // u32[120*4096]           1,966,080
#define WS_SS      12326400      // f32[120*4096]           1,966,080
#define WS_SS2     14292480      // f32[120*4096]           1,966,080
#define WS_BN2C    16258560      // f32[256]  (c1q[j], c0[128+j])
#define WS_OQ      16259584      // u32[BATCH]              1,048,576
#define WS_OACC    17308160      // u32 oS[2]@0; u64 oS2[2]@16; u32 yflag@32
#define WS_TOTAL   17308224

// Pack conv_w via ballots (coalesced) in the permuted bit order of the x
// packing: col c -> word (c&1), bit (c>>1). Zero pad columns, pack lin_w
// binarize, zero k3 accumulators, and set yflag if ANY conv_w element is
// exactly 0.0 (probability ~0 for this data, but must stay correct).
__global__ __launch_bounds__(256) void kw_pack(
        const float* __restrict__ w, const float* __restrict__ lw,
        u64* __restrict__ wbits, u32* __restrict__ lwq, u32* __restrict__ oaccz) {
    int tid = threadIdx.x, lane = tid & 63, wv = tid >> 6;
    if (tid < 12) oaccz[tid] = 0;      // oS[2], pad, oS2[2], yflag
    __syncthreads();
    u64 accy = 0;
    for (int j = wv; j < DIM; j += 4) {
        float2 v = make_float2(-1.f, -1.f);
        if (lane < 60) v = *(const float2*)(w + (size_t)j * DIM + lane * 2);
        u64 pe = __ballot(v.x > 0.f);
        u64 po = __ballot(v.y > 0.f);
        u64 ze = __ballot(v.x == 0.f);
        u64 zo = __ballot(v.y == 0.f);
        accy |= (ze | zo);
        if (lane == 0) {
            wbits[j*4+0] = pe; wbits[j*4+1] = po;
            wbits[j*4+2] = ze; wbits[j*4+3] = zo;
        }
    }
    if (lane == 0 && accy) atomicOr(&oaccz[8], 1u);
    if (tid >= 120 && tid < 128) {        // zero pad columns
        wbits[tid*4+0] = 0; wbits[tid*4+1] = 0;
        wbits[tid*4+2] = 0; wbits[tid*4+3] = 0;
    }
    if (tid < DIM) {
        float w0 = lw[tid], w1 = lw[DIM + tid];
        u32 l0 = w0 > 0.f ? 2u : (w0 == 0.f ? 1u : 0u);
        u32 l1 = w1 > 0.f ? 2u : (w1 == 0.f ? 1u : 0u);
        lwq[tid] = l0 | (l1 << 16);
    }
}

__device__ __forceinline__ u32 hq_from_bits(u64 p0, u64 p1, u64 z0, u64 z1,
                                            u64 q0, u64 q1, u64 y0, u64 y1,
                                            bool hasY, bool hasZ) {
    u32 hq = (u32)(__popcll(p0 & q0) + __popcll(p1 & q1)) << 2;
    if (hasY)
        hq += 2u * (u32)(__popcll(p0 & y0) + __popcll(p1 & y1))
            + (u32)(__popcll(z0 & y0) + __popcll(z1 & y1));
    if (hasZ)
        hq += 2u * (u32)(__popcll(z0 & q0) + __popcll(z1 & q1));
    return hq;   // == 4 * h, exact integer in [0, 480]
}

// K1: pack x into bits (ballot), store bits to global, compute integer
// per-column sums of hq and hq^2 (exact, deterministic).
__global__ __launch_bounds__(256) void k1_pack_hstats(
        const float* __restrict__ x, const u64* __restrict__ wbits,
        u64* __restrict__ xbits, u32* __restrict__ hS, u32* __restrict__ hS2) {
    __shared__ u64 lb[128][4];
    int tid = threadIdx.x, lane = tid & 63, wave = tid >> 6;
    size_t rowbase = (size_t)blockIdx.x * 128;

    for (int rr = 0; rr < 32; ++rr) {
        int r = wave * 32 + rr;
        float2 v = make_float2(-1.f, -1.f);
        if (lane < 60) v = *(const float2*)(x + (rowbase + r) * (size_t)DIM + lane * 2);
        u64 pe = __ballot(v.x > 0.f);
        u64 po = __ballot(v.y > 0.f);
        u64 ze = __ballot(v.x == 0.f);
        u64 zo = __ballot(v.y == 0.f);
        if (lane == 0) { lb[r][0] = pe; lb[r][1] = po; lb[r][2] = ze; lb[r][3] = zo; }
    }
    __syncthreads();
    ((ulonglong2*)(xbits + (size_t)blockIdx.x * 512))[tid] =
        ((const ulonglong2*)&lb[0][0])[tid];

    int j = tid & 127, half = tid >> 7;
    if (j < DIM) {
        u64 q0 = wbits[j*4+0], q1 = wbits[j*4+1], y0 = wbits[j*4+2], y1 = wbits[j*4+3];
        bool hasY = (y0 | y1) != 0;
        u32 S = 0, S2 = 0;
        int r0 = half * 64;
        for (int r = r0; r < r0 + 64; ++r) {
            u64 z0 = lb[r][2], z1 = lb[r][3];
            u32 hq = hq_from_bits(lb[r][0], lb[r][1], z0, z1,
                                  q0, q1, y0, y1, hasY, (z0 | z1) != 0);
            S += hq; S2 += hq * hq;
        }
        int pidx = j * NPART + blockIdx.x * 2 + half;
        hS[pidx] = S; hS2[pidx] = S2;
    }
}

// R1: reduce integer h-stats -> fold BN2 into  z = fma(hq, c1q, c0)
__global__ __launch_bounds__(256) void r1_hreduce(
        const u32* __restrict__ hS, const u32* __restrict__ hS2,
        const float* __restrict__ g2, const float* __restrict__ b2,
        float* __restrict__ bn2c) {
    int j = blockIdx.x, tid = threadIdx.x;
    u32 s = 0; u64 s2 = 0;
    for (int k = tid; k < NPART; k += 256) { s += hS[j*NPART+k]; s2 += (u64)hS2[j*NPART+k]; }
    for (int off = 32; off; off >>= 1) { s += __shfl_down(s, off, 64); s2 += __shfl_down(s2, off, 64); }
    __shared__ u32 as_[4]; __shared__ u64 as2_[4];
    int lane = tid & 63, wave = tid >> 6;
    if (lane == 0) { as_[wave] = s; as2_[wave] = s2; }
    __syncthreads();
    if (tid == 0) {
        u32 S = as_[0] + as_[1] + as_[2] + as_[3];
        u64 S2 = as2_[0] + as2_[1] + as2_[2] + as2_[3];
        double m2 = (double)S * 0.25 / (double)BATCH;
        double e2 = (double)S2 * 0.0625 / (double)BATCH;
        double v2 = e2 - m2 * m2;
        float rs = (float)(1.0 / sqrt(v2 + 1e-5));
        float c1 = rs * g2[j];
        float c0 = fmaf(-(float)m2, c1, b2[j]);
        bn2c[j]       = c1 * 0.25f;   // pre-scaled for hq (=4h)
        bn2c[128 + j] = c0;
    }
}

// K2: stage bits in LDS, recompute hq, softsign stats (dual f32 accumulators)
__global__ __launch_bounds__(256) void k2_sstats(
        const u64* __restrict__ xbits, const u64* __restrict__ wbits,
        const float* __restrict__ bn2c,
        float* __restrict__ sS, float* __restrict__ sS2) {
    __shared__ u64 lb[128][4];
    int tid = threadIdx.x;
    ((ulonglong2*)&lb[0][0])[tid] =
        ((const ulonglong2*)(xbits + (size_t)blockIdx.x * 512))[tid];
    __syncthreads();
    int j = tid & 127, half = tid >> 7;
    if (j >= DIM) return;
    u64 q0 = wbits[j*4+0], q1 = wbits[j*4+1], y0 = wbits[j*4+2], y1 = wbits[j*4+3];
    bool hasY = (y0 | y1) != 0;
    float c1q = bn2c[j], c0 = bn2c[128 + j];
    float SsA = 0.f, Ss2A = 0.f, SsB = 0.f, Ss2B = 0.f;
    int r0 = half * 64;
    for (int r = r0; r < r0 + 64; r += 2) {
        u64 z0 = lb[r][2], z1 = lb[r][3];
        u32 hqa = hq_from_bits(lb[r][0], lb[r][1], z0, z1,
                               q0, q1, y0, y1, hasY, (z0 | z1) != 0);
        u64 w0 = lb[r+1][2], w1 = lb[r+1][3];
        u32 hqb = hq_from_bits(lb[r+1][0], lb[r+1][1], w0, w1,
                               q0, q1, y0, y1, hasY, (w0 | w1) != 0);
        float za = fmaf((float)hqa, c1q, c0);
        float sa = za * __builtin_amdgcn_rcpf(1.f + fabsf(za));
        SsA += sa; Ss2A = fmaf(sa, sa, Ss2A);
        float zb = fmaf((float)hqb, c1q, c0);
        float sb = zb * __builtin_amdgcn_rcpf(1.f + fabsf(zb));
        SsB += sb; Ss2B = fmaf(sb, sb, Ss2B);
    }
    int pidx = j * NPART + blockIdx.x * 2 + half;
    sS[pidx] = SsA + SsB; sS2[pidx] = Ss2A + Ss2B;
}

// R2: reduce softsign stats (f64), fold BN1, derive the two integer
// thresholds per column (h1(hq) monotone in hq), pack meta words:
//   meta[2j]   = A | B<<9 | dec<<18     (hq units, A,B <= 482)
//   meta[2j+1] = lw0 | lw1<<16          (2*binarize of lin_w)
__global__ __launch_bounds__(256) void r2_sreduce(
        const float* __restrict__ sS, const float* __restrict__ sS2,
        const float* __restrict__ g1, const float* __restrict__ b1,
        const float* __restrict__ bn2c, const u32* __restrict__ lwq,
        u32* __restrict__ meta) {
    int j = blockIdx.x, tid = threadIdx.x;
    double s = 0.0, s2 = 0.0;
    for (int k = tid; k < NPART; k += 256) { s += (double)sS[j*NPART+k]; s2 += (double)sS2[j*NPART+k]; }
    for (int off = 32; off; off >>= 1) { s += __shfl_down(s, off, 64); s2 += __shfl_down(s2, off, 64); }
    __shared__ double ds_[4], ds2_[4];
    __shared__ float sd1, sd0;
    __shared__ u32 cnt[3];
    __shared__ u32 sfirst, slast;
    int lane = tid & 63, wave = tid >> 6;
    if (lane == 0) { ds_[wave] = s; ds2_[wave] = s2; }
    if (tid < 3) cnt[tid] = 0;
    __syncthreads();
    if (tid == 0) {
        double S = ds_[0] + ds_[1] + ds_[2] + ds_[3];
        double S2 = ds2_[0] + ds2_[1] + ds2_[2] + ds2_[3];
        double m1 = S / (double)BATCH;
        double v1 = S2 / (double)BATCH - m1 * m1;
        float rs = (float)(1.0 / sqrt(v1 + 1e-5));
        float d1 = rs * g1[j];
        float d0 = fmaf(-(float)m1, d1, b1[j]);
        sd1 = d1; sd0 = d0;
    }
    __syncthreads();
    float c1q = bn2c[j], c0 = bn2c[128 + j];
    float d1 = sd1, d0 = sd0;
    for (int hq = tid; hq < 481; hq += 256) {
        float z = fmaf((float)hq, c1q, c0);
        float sv = z * __builtin_amdgcn_rcpf(1.f + fabsf(z));
        float h1 = fmaf(sv, d1, d0);
        u32 hb2 = h1 > 0.f ? 2u : (h1 == 0.f ? 1u : 0u);
        atomicAdd(&cnt[hb2], 1u);
        if (hq == 0)   sfirst = hb2;
        if (hq == 480) slast  = hb2;
    }
    __syncthreads();
    if (tid == 0) {
        u32 n0 = cnt[0], n1 = cnt[1], n2 = cnt[2];
        u32 dec = (slast < sfirst) ? 1u : 0u;
        u32 A = dec ? n2 : n0;
        u32 B = A + n1;
        meta[2*j]   = A | (B << 9) | (dec << 18);
        meta[2*j+1] = lwq[j];
    }
}

__device__ __forceinline__ u32 thr_hb2(u32 hq, u32 t) {
    u32 ge = (u32)(hq >= (t & 511u)) + (u32)(hq >= ((t >> 9) & 511u));
    return (t & (1u << 18)) ? 2u - ge : ge;
}

// K3: thread <-> 2 rows. Per-column state (q-bits 16B + meta 8B) staged once
// in 3KB LDS, read wave-uniform (broadcast) in an unrolled branch-free loop:
// 6 independent ds_read pairs in flight, 2-row ILP. Exact-zero x rows
// (expected ~2 in 262144) fixed up in a rare divergent tail; exact-zero
// conv_w (yflag, probability ~0) falls back to a full path.
__global__ __launch_bounds__(128) void k3_out(
        const u64* __restrict__ xbits, const u64* __restrict__ wbits,
        const u32* __restrict__ meta, const u32* __restrict__ oacc,
        u32* __restrict__ oqbuf, u32* __restrict__ oS, u64* __restrict__ oS2) {
    __shared__ u64 sq[DIM][2];
    __shared__ u32 sm[DIM * 2];
    int tid = threadIdx.x;
    for (int k = tid; k < DIM * 2; k += 128) {
        ((u64*)sq)[k] = wbits[(k >> 1) * 4 + (k & 1)];
        sm[k] = meta[k];
    }
    __syncthreads();
    size_t row0 = (size_t)blockIdx.x * 256 + tid;
    size_t row1 = row0 + 128;
    const ulonglong2* xb = (const ulonglong2*)xbits;
    ulonglong2 ra0 = xb[row0*2], ra1 = xb[row0*2+1];
    ulonglong2 rb0 = xb[row1*2], rb1 = xb[row1*2+1];
    u64 pA0 = ra0.x, pA1 = ra0.y, zA0 = ra1.x, zA1 = ra1.y;
    u64 pB0 = rb0.x, pB1 = rb0.y, zB0 = rb1.x, zB1 = rb1.y;
    u32 oqA = 0, oqB = 0;
    if (oacc[8] == 0) {                 // no exact-zero conv_w anywhere
        #pragma unroll 6
        for (int j = 0; j < DIM; ++j) {
            u64 q0 = sq[j][0], q1 = sq[j][1];
            u32 t = sm[2*j], lwp = sm[2*j+1];
            u32 hqA = ((u32)(__popcll(pA0 & q0) + __popcll(pA1 & q1))) << 2;
            u32 hqB = ((u32)(__popcll(pB0 & q0) + __popcll(pB1 & q1))) << 2;
            oqA += thr_hb2(hqA, t) * lwp;
            oqB += thr_hb2(hqB, t) * lwp;
        }
        if (__any((zA0 | zA1) != 0)) {  // rare: row0 has exact-zero x
            if (zA0 | zA1) {
                oqA = 0;
                for (int j = 0; j < DIM; ++j) {
                    u64 q0 = sq[j][0], q1 = sq[j][1];
                    u64 y0 = wbits[j*4+2], y1 = wbits[j*4+3];
                    u32 hq = hq_from_bits(pA0, pA1, zA0, zA1, q0, q1, y0, y1,
                                          (y0 | y1) != 0, true);
                    oqA += thr_hb2(hq, sm[2*j]) * sm[2*j+1];
                }
            }
        }
        if (__any((zB0 | zB1) != 0)) {  // rare: row1 has exact-zero x
            if (zB0 | zB1) {
                oqB = 0;
                for (int j = 0; j < DIM; ++j) {
                    u64 q0 = sq[j][0], q1 = sq[j][1];
                    u64 y0 = wbits[j*4+2], y1 = wbits[j*4+3];
                    u32 hq = hq_from_bits(pB0, pB1, zB0, zB1, q0, q1, y0, y1,
                                          (y0 | y1) != 0, true);
                    oqB += thr_hb2(hq, sm[2*j]) * sm[2*j+1];
                }
            }
        }
    } else {                            // full path (never for this data)
        for (int j = 0; j < DIM; ++j) {
            u64 q0 = sq[j][0], q1 = sq[j][1];
            u64 y0 = wbits[j*4+2], y1 = wbits[j*4+3];
            bool hasY = (y0 | y1) != 0;
            u32 t = sm[2*j], lwp = sm[2*j+1];
            u32 hqA = hq_from_bits(pA0, pA1, zA0, zA1, q0, q1, y0, y1,
                                   hasY, (zA0 | zA1) != 0);
            u32 hqB = hq_from_bits(pB0, pB1, zB0, zB1, q0, q1, y0, y1,
                                   hasY, (zB0 | zB1) != 0);
            oqA += thr_hb2(hqA, t) * lwp;
            oqB += thr_hb2(hqB, t) * lwp;
        }
    }
    oqbuf[row0] = oqA; oqbuf[row1] = oqB;
    u32 oa0 = oqA & 0xffffu, oa1 = oqA >> 16;
    u32 ob0 = oqB & 0xffffu, ob1 = oqB >> 16;
    u32 a = oa0 + ob0, b = oa1 + ob1;
    u32 c2 = oa0*oa0 + ob0*ob0, d2 = oa1*oa1 + ob1*ob1;
    for (int off = 32; off; off >>= 1) {
        a += __shfl_down(a, off, 64);  b += __shfl_down(b, off, 64);
        c2 += __shfl_down(c2, off, 64); d2 += __shfl_down(d2, off, 64);
    }
    __shared__ u32 r0_[2], r1_[2], r2_[2], r3_[2];
    int lane = tid & 63, wv = tid >> 6;
    if (lane == 0) { r0_[wv] = a; r1_[wv] = b; r2_[wv] = c2; r3_[wv] = d2; }
    __syncthreads();
    if (tid == 0) {
        atomicAdd(&oS[0], r0_[0] + r0_[1]);
        atomicAdd(&oS[1], r1_[0] + r1_[1]);
        atomicAdd(&oS2[0], (u64)(r2_[0] + r2_[1]));
        atomicAdd(&oS2[1], (u64)(r3_[0] + r3_[1]));
    }
}

// K4: finalize output BN constants in-block (lin_b cancels through the
// no-affine BN), then normalize + 2-class log_softmax.
__global__ __launch_bounds__(256) void k4_final(
        const u32* __restrict__ oqbuf, const u32* __restrict__ oS,
        const u64* __restrict__ oS2, float* __restrict__ out) {
    __shared__ float sfin[4];
    int tid = threadIdx.x;
    if (tid < 2) {
        double a  = (double)oS[tid] * 0.25 / (double)BATCH;
        double e2 = (double)oS2[tid] * 0.0625 / (double)BATCH;
        double vo = e2 - a * a;
        sfin[tid]     = (float)a;
        sfin[2 + tid] = (float)(1.0 / sqrt(vo + 1e-5));
    }
    __syncthreads();
    size_t row = (size_t)blockIdx.x * 256 + tid;
    u32 v = oqbuf[row];
    float o0 = ((float)(v & 0xffffu) * 0.25f - sfin[0]) * sfin[2];
    float o1 = ((float)(v >> 16)     * 0.25f - sfin[1]) * sfin[3];
    float m = fmaxf(o0, o1);
    float l0 = o0 - m, l1 = o1 - m;
    float ls = logf(expf(l0) + expf(l1));
    ((float2*)out)[row] = make_float2(l0 - ls, l1 - ls);
}

extern "C" void kernel_launch(void* const* d_in, const int* in_sizes, int n_in,
                              void* d_out, int out_size, void* d_ws, size_t ws_size,
                              hipStream_t stream) {
    const float* x  = (const float*)d_in[0];
    const float* cw = (const float*)d_in[1];
    const float* g2 = (const float*)d_in[2];
    const float* b2 = (const float*)d_in[3];
    const float* g1 = (const float*)d_in[4];
    const float* b1 = (const float*)d_in[5];
    const float* lw = (const float*)d_in[6];
    // d_in[7] (lin_b) cancels through the final no-affine batchnorm
    float* out = (float*)d_out;
    if (ws_size < (size_t)WS_TOTAL) return;   // fail loudly via poisoned d_out

    char* ws = (char*)d_ws;
    u64* xbits = (u64*)(ws + WS_XBITS);
    u64* wbits = (u64*)(ws + WS_WBITS);
    u32* lwq   = (u32*)(ws + WS_LWQ);
    u32* meta  = (u32*)(ws + WS_META);
    u32* hS    = (u32*)(ws + WS_HS);
    u32* hS2   = (u32*)(ws + WS_HS2);
    float* sS  = (float*)(ws + WS_SS);
    float* sS2 = (float*)(ws + WS_SS2);
    float* bn2c = (float*)(ws + WS_BN2C);
    u32* oqbuf = (u32*)(ws + WS_OQ);
    u32* oS    = (u32*)(ws + WS_OACC);
    u64* oS2   = (u64*)(ws + WS_OACC + 16);

    kw_pack       <<<1, 256, 0, stream>>>(cw, lw, wbits, lwq, oS);
    k1_pack_hstats<<<NBLK1, 256, 0, stream>>>(x, wbits, xbits, hS, hS2);
    r1_hreduce    <<<DIM, 256, 0, stream>>>(hS, hS2, g2, b2, bn2c);
    k2_sstats     <<<NBLK1, 256, 0, stream>>>(xbits, wbits, bn2c, sS, sS2);
    r2_sreduce    <<<DIM, 256, 0, stream>>>(sS, sS2, g1, b1, bn2c, lwq, meta);
    k3_out        <<<BATCH/256, 128, 0, stream>>>(xbits, wbits, meta, oS, oqbuf, oS, oS2);
    k4_final      <<<BATCH/256, 256, 0, stream>>>(oqbuf, oS, oS2, out);
}

// Round 6
// 151.243 us; speedup vs baseline: 1.3717x; 1.0254x over previous
//
#include <hip/hip_runtime.h>
#include <stdint.h>
#include <math.h>

typedef unsigned long long u64;
typedef uint32_t u32;

#define BATCH   262144
#define DIM     120
#define NBLK1   2048      // K1/K2: 128 rows per block
#define NPART   4096      // partial slots per column (2 halves * 2048 blocks)
#define CH      8         // k3: columns per register chunk

// ---------------- workspace layout (bytes) ----------------
#define WS_XBITS   0              // u64[BATCH*4]            8,388,608
#define WS_WBITS   8388608        // u64[128*4]                  4,096
#define WS_LWQ     8392704        // u32[128]                      512
#define WS_META    8393216        // u32[256] (2 per col)        1,024
#define WS_HS      8394240        // u32[120*4096]           1,966,080
#define WS_HS2     10360320      // u32[120*4096]           1,966,080
#define WS_SS      12326400      // f32[120*4096]           1,966,080
#define WS_SS2     14292480      // f32[120*4096]           1,966,080
#define WS_BN2C    16258560      // f32[256]  (c1q[j], c0[128+j])
#define WS_OQ      16259584      // u32[BATCH]              1,048,576
#define WS_OACC    17308160      // u32 oS[2]@0; u64 oS2[2]@16; u32 yflag@32
#define WS_TOTAL   17308224

// Pack conv_w via ballots (coalesced) in the permuted bit order of the x
// packing: col c -> word (c&1), bit (c>>1). Zero pad columns, pack lin_w
// binarize, zero k3 accumulators, and set yflag if ANY conv_w element is
// exactly 0.0 (probability ~0 for this data, but must stay correct).
__global__ __launch_bounds__(256) void kw_pack(
        const float* __restrict__ w, const float* __restrict__ lw,
        u64* __restrict__ wbits, u32* __restrict__ lwq, u32* __restrict__ oaccz) {
    int tid = threadIdx.x, lane = tid & 63, wv = tid >> 6;
    if (tid < 12) oaccz[tid] = 0;      // oS[2], pad, oS2[2], yflag
    __syncthreads();
    u64 accy = 0;
    for (int j = wv; j < DIM; j += 4) {
        float2 v = make_float2(-1.f, -1.f);
        if (lane < 60) v = *(const float2*)(w + (size_t)j * DIM + lane * 2);
        u64 pe = __ballot(v.x > 0.f);
        u64 po = __ballot(v.y > 0.f);
        u64 ze = __ballot(v.x == 0.f);
        u64 zo = __ballot(v.y == 0.f);
        accy |= (ze | zo);
        if (lane == 0) {
            wbits[j*4+0] = pe; wbits[j*4+1] = po;
            wbits[j*4+2] = ze; wbits[j*4+3] = zo;
        }
    }
    if (lane == 0 && accy) atomicOr(&oaccz[8], 1u);
    if (tid >= 120 && tid < 128) {        // zero pad columns
        wbits[tid*4+0] = 0; wbits[tid*4+1] = 0;
        wbits[tid*4+2] = 0; wbits[tid*4+3] = 0;
    }
    if (tid < DIM) {
        float w0 = lw[tid], w1 = lw[DIM + tid];
        u32 l0 = w0 > 0.f ? 2u : (w0 == 0.f ? 1u : 0u);
        u32 l1 = w1 > 0.f ? 2u : (w1 == 0.f ? 1u : 0u);
        lwq[tid] = l0 | (l1 << 16);
    }
}

__device__ __forceinline__ u32 hq_from_bits(u64 p0, u64 p1, u64 z0, u64 z1,
                                            u64 q0, u64 q1, u64 y0, u64 y1,
                                            bool hasY, bool hasZ) {
    u32 hq = (u32)(__popcll(p0 & q0) + __popcll(p1 & q1)) << 2;
    if (hasY)
        hq += 2u * (u32)(__popcll(p0 & y0) + __popcll(p1 & y1))
            + (u32)(__popcll(z0 & y0) + __popcll(z1 & y1));
    if (hasZ)
        hq += 2u * (u32)(__popcll(z0 & q0) + __popcll(z1 & q1));
    return hq;   // == 4 * h, exact integer in [0, 480]
}

// K1: pack x into bits (ballot), store bits to global, compute integer
// per-column sums of hq and hq^2 (exact, deterministic).
__global__ __launch_bounds__(256) void k1_pack_hstats(
        const float* __restrict__ x, const u64* __restrict__ wbits,
        u64* __restrict__ xbits, u32* __restrict__ hS, u32* __restrict__ hS2) {
    __shared__ u64 lb[128][4];
    int tid = threadIdx.x, lane = tid & 63, wave = tid >> 6;
    size_t rowbase = (size_t)blockIdx.x * 128;

    for (int rr = 0; rr < 32; ++rr) {
        int r = wave * 32 + rr;
        float2 v = make_float2(-1.f, -1.f);
        if (lane < 60) v = *(const float2*)(x + (rowbase + r) * (size_t)DIM + lane * 2);
        u64 pe = __ballot(v.x > 0.f);
        u64 po = __ballot(v.y > 0.f);
        u64 ze = __ballot(v.x == 0.f);
        u64 zo = __ballot(v.y == 0.f);
        if (lane == 0) { lb[r][0] = pe; lb[r][1] = po; lb[r][2] = ze; lb[r][3] = zo; }
    }
    __syncthreads();
    ((ulonglong2*)(xbits + (size_t)blockIdx.x * 512))[tid] =
        ((const ulonglong2*)&lb[0][0])[tid];

    int j = tid & 127, half = tid >> 7;
    if (j < DIM) {
        u64 q0 = wbits[j*4+0], q1 = wbits[j*4+1], y0 = wbits[j*4+2], y1 = wbits[j*4+3];
        bool hasY = (y0 | y1) != 0;
        u32 S = 0, S2 = 0;
        int r0 = half * 64;
        for (int r = r0; r < r0 + 64; ++r) {
            u64 z0 = lb[r][2], z1 = lb[r][3];
            u32 hq = hq_from_bits(lb[r][0], lb[r][1], z0, z1,
                                  q0, q1, y0, y1, hasY, (z0 | z1) != 0);
            S += hq; S2 += hq * hq;
        }
        int pidx = j * NPART + blockIdx.x * 2 + half;
        hS[pidx] = S; hS2[pidx] = S2;
    }
}

// R1: reduce integer h-stats -> fold BN2 into  z = fma(hq, c1q, c0)
__global__ __launch_bounds__(256) void r1_hreduce(
        const u32* __restrict__ hS, const u32* __restrict__ hS2,
        const float* __restrict__ g2, const float* __restrict__ b2,
        float* __restrict__ bn2c) {
    int j = blockIdx.x, tid = threadIdx.x;
    u32 s = 0; u64 s2 = 0;
    for (int k = tid; k < NPART; k += 256) { s += hS[j*NPART+k]; s2 += (u64)hS2[j*NPART+k]; }
    for (int off = 32; off; off >>= 1) { s += __shfl_down(s, off, 64); s2 += __shfl_down(s2, off, 64); }
    __shared__ u32 as_[4]; __shared__ u64 as2_[4];
    int lane = tid & 63, wave = tid >> 6;
    if (lane == 0) { as_[wave] = s; as2_[wave] = s2; }
    __syncthreads();
    if (tid == 0) {
        u32 S = as_[0] + as_[1] + as_[2] + as_[3];
        u64 S2 = as2_[0] + as2_[1] + as2_[2] + as2_[3];
        double m2 = (double)S * 0.25 / (double)BATCH;
        double e2 = (double)S2 * 0.0625 / (double)BATCH;
        double v2 = e2 - m2 * m2;
        float rs = (float)(1.0 / sqrt(v2 + 1e-5));
        float c1 = rs * g2[j];
        float c0 = fmaf(-(float)m2, c1, b2[j]);
        bn2c[j]       = c1 * 0.25f;   // pre-scaled for hq (=4h)
        bn2c[128 + j] = c0;
    }
}

// K2: stage bits in LDS, recompute hq, softsign stats (dual f32 accumulators)
__global__ __launch_bounds__(256) void k2_sstats(
        const u64* __restrict__ xbits, const u64* __restrict__ wbits,
        const float* __restrict__ bn2c,
        float* __restrict__ sS, float* __restrict__ sS2) {
    __shared__ u64 lb[128][4];
    int tid = threadIdx.x;
    ((ulonglong2*)&lb[0][0])[tid] =
        ((const ulonglong2*)(xbits + (size_t)blockIdx.x * 512))[tid];
    __syncthreads();
    int j = tid & 127, half = tid >> 7;
    if (j >= DIM) return;
    u64 q0 = wbits[j*4+0], q1 = wbits[j*4+1], y0 = wbits[j*4+2], y1 = wbits[j*4+3];
    bool hasY = (y0 | y1) != 0;
    float c1q = bn2c[j], c0 = bn2c[128 + j];
    float SsA = 0.f, Ss2A = 0.f, SsB = 0.f, Ss2B = 0.f;
    int r0 = half * 64;
    for (int r = r0; r < r0 + 64; r += 2) {
        u64 z0 = lb[r][2], z1 = lb[r][3];
        u32 hqa = hq_from_bits(lb[r][0], lb[r][1], z0, z1,
                               q0, q1, y0, y1, hasY, (z0 | z1) != 0);
        u64 w0 = lb[r+1][2], w1 = lb[r+1][3];
        u32 hqb = hq_from_bits(lb[r+1][0], lb[r+1][1], w0, w1,
                               q0, q1, y0, y1, hasY, (w0 | w1) != 0);
        float za = fmaf((float)hqa, c1q, c0);
        float sa = za * __builtin_amdgcn_rcpf(1.f + fabsf(za));
        SsA += sa; Ss2A = fmaf(sa, sa, Ss2A);
        float zb = fmaf((float)hqb, c1q, c0);
        float sb = zb * __builtin_amdgcn_rcpf(1.f + fabsf(zb));
        SsB += sb; Ss2B = fmaf(sb, sb, Ss2B);
    }
    int pidx = j * NPART + blockIdx.x * 2 + half;
    sS[pidx] = SsA + SsB; sS2[pidx] = Ss2A + Ss2B;
}

// R2: reduce softsign stats (f64), fold BN1, derive the two integer
// thresholds per column (h1(hq) monotone in hq), pack meta words:
//   meta[2j]   = A | B<<9 | dec<<18     (hq units, A,B <= 482)
//   meta[2j+1] = lw0 | lw1<<16          (2*binarize of lin_w)
__global__ __launch_bounds__(256) void r2_sreduce(
        const float* __restrict__ sS, const float* __restrict__ sS2,
        const float* __restrict__ g1, const float* __restrict__ b1,
        const float* __restrict__ bn2c, const u32* __restrict__ lwq,
        u32* __restrict__ meta) {
    int j = blockIdx.x, tid = threadIdx.x;
    double s = 0.0, s2 = 0.0;
    for (int k = tid; k < NPART; k += 256) { s += (double)sS[j*NPART+k]; s2 += (double)sS2[j*NPART+k]; }
    for (int off = 32; off; off >>= 1) { s += __shfl_down(s, off, 64); s2 += __shfl_down(s2, off, 64); }
    __shared__ double ds_[4], ds2_[4];
    __shared__ float sd1, sd0;
    __shared__ u32 cnt[3];
    __shared__ u32 sfirst, slast;
    int lane = tid & 63, wave = tid >> 6;
    if (lane == 0) { ds_[wave] = s; ds2_[wave] = s2; }
    if (tid < 3) cnt[tid] = 0;
    __syncthreads();
    if (tid == 0) {
        double S = ds_[0] + ds_[1] + ds_[2] + ds_[3];
        double S2 = ds2_[0] + ds2_[1] + ds2_[2] + ds2_[3];
        double m1 = S / (double)BATCH;
        double v1 = S2 / (double)BATCH - m1 * m1;
        float rs = (float)(1.0 / sqrt(v1 + 1e-5));
        float d1 = rs * g1[j];
        float d0 = fmaf(-(float)m1, d1, b1[j]);
        sd1 = d1; sd0 = d0;
    }
    __syncthreads();
    float c1q = bn2c[j], c0 = bn2c[128 + j];
    float d1 = sd1, d0 = sd0;
    for (int hq = tid; hq < 481; hq += 256) {
        float z = fmaf((float)hq, c1q, c0);
        float sv = z * __builtin_amdgcn_rcpf(1.f + fabsf(z));
        float h1 = fmaf(sv, d1, d0);
        u32 hb2 = h1 > 0.f ? 2u : (h1 == 0.f ? 1u : 0u);
        atomicAdd(&cnt[hb2], 1u);
        if (hq == 0)   sfirst = hb2;
        if (hq == 480) slast  = hb2;
    }
    __syncthreads();
    if (tid == 0) {
        u32 n0 = cnt[0], n1 = cnt[1], n2 = cnt[2];
        u32 dec = (slast < sfirst) ? 1u : 0u;
        u32 A = dec ? n2 : n0;
        u32 B = A + n1;
        meta[2*j]   = A | (B << 9) | (dec << 18);
        meta[2*j+1] = lwq[j];
    }
}

__device__ __forceinline__ void proc_col(u64 p0, u64 p1, u64 q0, u64 q1,
                                         u64 mw, u32& oq) {
    u32 hq = ((u32)(__popcll(p0 & q0) + __popcll(p1 & q1))) << 2;
    u32 m  = (u32)mw;
    u32 lw = (u32)(mw >> 32);
    u32 ge = (u32)(hq >= (m & 511u)) + (u32)(hq >= ((m >> 9) & 511u));
    u32 hb2 = (m & (1u << 18)) ? 2u - ge : ge;
    oq += hb2 * lw;            // low16: class0, high16: class1
}

// K3: thread <-> row (256 thr, 1024 blocks = 4 waves/SIMD). Column state
// staged once to LDS, then consumed in CHUNKS of 8 columns: 12 independent
// uniform ds_read_b128 into statically-indexed registers, then 8 pure-VALU
// column steps — one waitcnt per chunk instead of one per column. Rare
// exact-zero x rows (and the ~impossible conv_w-zero yflag) take a divergent
// fixup path after the fast loop.
__global__ __launch_bounds__(256) void k3_out(
        const u64* __restrict__ xbits, const u64* __restrict__ wbits,
        const u32* __restrict__ meta, const u32* __restrict__ oacc,
        u32* __restrict__ oqbuf, u32* __restrict__ oS, u64* __restrict__ oS2) {
    __shared__ u64 sq0[DIM], sq1[DIM], smw[DIM], sy0[DIM], sy1[DIM];
    int tid = threadIdx.x;
    for (int k = tid; k < DIM; k += 256) {
        sq0[k] = wbits[k*4+0]; sq1[k] = wbits[k*4+1];
        sy0[k] = wbits[k*4+2]; sy1[k] = wbits[k*4+3];
        smw[k] = (u64)meta[2*k] | ((u64)meta[2*k+1] << 32);
    }
    __syncthreads();
    size_t row = (size_t)blockIdx.x * 256 + tid;
    const ulonglong2* xb = (const ulonglong2*)xbits;
    ulonglong2 rp = xb[row*2], rz = xb[row*2+1];
    u64 p0 = rp.x, p1 = rp.y, z0 = rz.x, z1 = rz.y;
    u32 oq = 0;
    for (int c = 0; c < DIM; c += CH) {
        ulonglong2 A[CH/2], B[CH/2], M[CH/2];
        #pragma unroll
        for (int t = 0; t < CH/2; ++t) {
            A[t] = *(const ulonglong2*)&sq0[c + 2*t];
            B[t] = *(const ulonglong2*)&sq1[c + 2*t];
            M[t] = *(const ulonglong2*)&smw[c + 2*t];
        }
        #pragma unroll
        for (int t = 0; t < CH/2; ++t) {
            proc_col(p0, p1, A[t].x, B[t].x, M[t].x, oq);
            proc_col(p0, p1, A[t].y, B[t].y, M[t].y, oq);
        }
    }
    bool slow = (oacc[8] != 0) | ((z0 | z1) != 0);
    if (__any(slow)) {
        if (slow) {          // exact full recompute (expected ~2 rows/batch)
            oq = 0;
            for (int j = 0; j < DIM; ++j) {
                u64 y0 = sy0[j], y1 = sy1[j];
                u32 hq = hq_from_bits(p0, p1, z0, z1, sq0[j], sq1[j], y0, y1,
                                      (y0 | y1) != 0, (z0 | z1) != 0);
                u64 mw = smw[j];
                u32 m = (u32)mw, lw = (u32)(mw >> 32);
                u32 ge = (u32)(hq >= (m & 511u)) + (u32)(hq >= ((m >> 9) & 511u));
                oq += ((m & (1u << 18)) ? 2u - ge : ge) * lw;
            }
        }
    }
    oqbuf[row] = oq;
    u32 o0 = oq & 0xffffu, o1 = oq >> 16;
    u32 a = o0, b = o1, c2 = o0 * o0, d2 = o1 * o1;
    for (int off = 32; off; off >>= 1) {
        a += __shfl_down(a, off, 64);  b += __shfl_down(b, off, 64);
        c2 += __shfl_down(c2, off, 64); d2 += __shfl_down(d2, off, 64);
    }
    __shared__ u32 r0_[4], r1_[4], r2_[4], r3_[4];
    int lane = tid & 63, wv = tid >> 6;
    if (lane == 0) { r0_[wv] = a; r1_[wv] = b; r2_[wv] = c2; r3_[wv] = d2; }
    __syncthreads();
    if (tid == 0) {
        atomicAdd(&oS[0], r0_[0] + r0_[1] + r0_[2] + r0_[3]);
        atomicAdd(&oS[1], r1_[0] + r1_[1] + r1_[2] + r1_[3]);
        atomicAdd(&oS2[0], (u64)(r2_[0] + r2_[1] + r2_[2] + r2_[3]));
        atomicAdd(&oS2[1], (u64)(r3_[0] + r3_[1] + r3_[2] + r3_[3]));
    }
}

// K4: finalize output BN constants in-block (lin_b cancels through the
// no-affine BN), then normalize + 2-class log_softmax.
__global__ __launch_bounds__(256) void k4_final(
        const u32* __restrict__ oqbuf, const u32* __restrict__ oS,
        const u64* __restrict__ oS2, float* __restrict__ out) {
    __shared__ float sfin[4];
    int tid = threadIdx.x;
    if (tid < 2) {
        double a  = (double)oS[tid] * 0.25 / (double)BATCH;
        double e2 = (double)oS2[tid] * 0.0625 / (double)BATCH;
        double vo = e2 - a * a;
        sfin[tid]     = (float)a;
        sfin[2 + tid] = (float)(1.0 / sqrt(vo + 1e-5));
    }
    __syncthreads();
    size_t row = (size_t)blockIdx.x * 256 + tid;
    u32 v = oqbuf[row];
    float o0 = ((float)(v & 0xffffu) * 0.25f - sfin[0]) * sfin[2];
    float o1 = ((float)(v >> 16)     * 0.25f - sfin[1]) * sfin[3];
    float m = fmaxf(o0, o1);
    float l0 = o0 - m, l1 = o1 - m;
    float ls = logf(expf(l0) + expf(l1));
    ((float2*)out)[row] = make_float2(l0 - ls, l1 - ls);
}

extern "C" void kernel_launch(void* const* d_in, const int* in_sizes, int n_in,
                              void* d_out, int out_size, void* d_ws, size_t ws_size,
                              hipStream_t stream) {
    const float* x  = (const float*)d_in[0];
    const float* cw = (const float*)d_in[1];
    const float* g2 = (const float*)d_in[2];
    const float* b2 = (const float*)d_in[3];
    const float* g1 = (const float*)d_in[4];
    const float* b1 = (const float*)d_in[5];
    const float* lw = (const float*)d_in[6];
    // d_in[7] (lin_b) cancels through the final no-affine batchnorm
    float* out = (float*)d_out;
    if (ws_size < (size_t)WS_TOTAL) return;   // fail loudly via poisoned d_out

    char* ws = (char*)d_ws;
    u64* xbits = (u64*)(ws + WS_XBITS);
    u64* wbits = (u64*)(ws + WS_WBITS);
    u32* lwq   = (u32*)(ws + WS_LWQ);
    u32* meta  = (u32*)(ws + WS_META);
    u32* hS    = (u32*)(ws + WS_HS);
    u32* hS2   = (u32*)(ws + WS_HS2);
    float* sS  = (float*)(ws + WS_SS);
    float* sS2 = (float*)(ws + WS_SS2);
    float* bn2c = (float*)(ws + WS_BN2C);
    u32* oqbuf = (u32*)(ws + WS_OQ);
    u32* oS    = (u32*)(ws + WS_OACC);
    u64* oS2   = (u64*)(ws + WS_OACC + 16);

    kw_pack       <<<1, 256, 0, stream>>>(cw, lw, wbits, lwq, oS);
    k1_pack_hstats<<<NBLK1, 256, 0, stream>>>(x, wbits, xbits, hS, hS2);
    r1_hreduce    <<<DIM, 256, 0, stream>>>(hS, hS2, g2, b2, bn2c);
    k2_sstats     <<<NBLK1, 256, 0, stream>>>(xbits, wbits, bn2c, sS, sS2);
    r2_sreduce    <<<DIM, 256, 0, stream>>>(sS, sS2, g1, b1, bn2c, lwq, meta);
    k3_out        <<<BATCH/256, 256, 0, stream>>>(xbits, wbits, meta, oS, oqbuf, oS, oS2);
    k4_final      <<<BATCH/256, 256, 0, stream>>>(oqbuf, oS, oS2, out);
}

// Round 7
// 115.529 us; speedup vs baseline: 1.7957x; 1.3091x over previous
//
#include <hip/hip_runtime.h>
#include <stdint.h>
#include <math.h>

typedef unsigned long long u64;
typedef uint32_t u32;

#define BATCH   262144
#define DIM     120
#define NBLK1   2048      // K1/K2: 128 rows per block
#define NPART   4096      // partial slots per column (2 halves * 2048 blocks)
#define CH      8         // k3: columns per register chunk
#define NBLK3   1024      // k3 blocks (256 rows each)

// ---------------- workspace layout (bytes) ----------------
#define WS_XBITS   0              // u64[BATCH*4]            8,388,608
#define WS_WBITS   8388608        // u64[128*4]                  4,096
#define WS_LWQ     8392704        // u32[128]                      512
#define WS_META    8393216        // u32[256] (2 per col)        1,024
#define WS_HS      8394240        // u32[120*4096]           1,966,080
#define WS_HS2     10360320      // u32[120*4096]           1,966,080
#define WS_SS      12326400      // f32[120*4096]           1,966,080
#define WS_SS2     14292480      // f32[120*4096]           1,966,080
#define WS_BN2C    16258560      // f32[256]  (c1q[j], c0[128+j])
#define WS_OQ      16259584      // u32[BATCH]              1,048,576
#define WS_OACC    17308160      // u32 yflag@32 (legacy slots 0..31 unused)
#define WS_OP      17308224      // u32[NBLK3*4] block partials    16,384
#define WS_FIN     17324608      // f32[4]                             16
#define WS_TOTAL   17324624

// Pack conv_w via ballots (coalesced) in the permuted bit order of the x
// packing: col c -> word (c&1), bit (c>>1). Zero pad columns, pack lin_w
// binarize, and set yflag if ANY conv_w element is exactly 0.0
// (probability ~0 for this data, but must stay correct).
__global__ __launch_bounds__(256) void kw_pack(
        const float* __restrict__ w, const float* __restrict__ lw,
        u64* __restrict__ wbits, u32* __restrict__ lwq, u32* __restrict__ oaccz) {
    int tid = threadIdx.x, lane = tid & 63, wv = tid >> 6;
    if (tid < 12) oaccz[tid] = 0;      // incl. yflag @ word 8
    __syncthreads();
    u64 accy = 0;
    for (int j = wv; j < DIM; j += 4) {
        float2 v = make_float2(-1.f, -1.f);
        if (lane < 60) v = *(const float2*)(w + (size_t)j * DIM + lane * 2);
        u64 pe = __ballot(v.x > 0.f);
        u64 po = __ballot(v.y > 0.f);
        u64 ze = __ballot(v.x == 0.f);
        u64 zo = __ballot(v.y == 0.f);
        accy |= (ze | zo);
        if (lane == 0) {
            wbits[j*4+0] = pe; wbits[j*4+1] = po;
            wbits[j*4+2] = ze; wbits[j*4+3] = zo;
        }
    }
    if (lane == 0 && accy) atomicOr(&oaccz[8], 1u);
    if (tid >= 120 && tid < 128) {        // zero pad columns
        wbits[tid*4+0] = 0; wbits[tid*4+1] = 0;
        wbits[tid*4+2] = 0; wbits[tid*4+3] = 0;
    }
    if (tid < DIM) {
        float w0 = lw[tid], w1 = lw[DIM + tid];
        u32 l0 = w0 > 0.f ? 2u : (w0 == 0.f ? 1u : 0u);
        u32 l1 = w1 > 0.f ? 2u : (w1 == 0.f ? 1u : 0u);
        lwq[tid] = l0 | (l1 << 16);
    }
}

__device__ __forceinline__ u32 hq_from_bits(u64 p0, u64 p1, u64 z0, u64 z1,
                                            u64 q0, u64 q1, u64 y0, u64 y1,
                                            bool hasY, bool hasZ) {
    u32 hq = (u32)(__popcll(p0 & q0) + __popcll(p1 & q1)) << 2;
    if (hasY)
        hq += 2u * (u32)(__popcll(p0 & y0) + __popcll(p1 & y1))
            + (u32)(__popcll(z0 & y0) + __popcll(z1 & y1));
    if (hasZ)
        hq += 2u * (u32)(__popcll(z0 & q0) + __popcll(z1 & q1));
    return hq;   // == 4 * h, exact integer in [0, 480]
}

// K1: pack x into bits (ballot), store bits to global, compute integer
// per-column sums of hq and hq^2 (exact, deterministic).
__global__ __launch_bounds__(256) void k1_pack_hstats(
        const float* __restrict__ x, const u64* __restrict__ wbits,
        u64* __restrict__ xbits, u32* __restrict__ hS, u32* __restrict__ hS2) {
    __shared__ u64 lb[128][4];
    int tid = threadIdx.x, lane = tid & 63, wave = tid >> 6;
    size_t rowbase = (size_t)blockIdx.x * 128;

    for (int rr = 0; rr < 32; ++rr) {
        int r = wave * 32 + rr;
        float2 v = make_float2(-1.f, -1.f);
        if (lane < 60) v = *(const float2*)(x + (rowbase + r) * (size_t)DIM + lane * 2);
        u64 pe = __ballot(v.x > 0.f);
        u64 po = __ballot(v.y > 0.f);
        u64 ze = __ballot(v.x == 0.f);
        u64 zo = __ballot(v.y == 0.f);
        if (lane == 0) { lb[r][0] = pe; lb[r][1] = po; lb[r][2] = ze; lb[r][3] = zo; }
    }
    __syncthreads();
    ((ulonglong2*)(xbits + (size_t)blockIdx.x * 512))[tid] =
        ((const ulonglong2*)&lb[0][0])[tid];

    int j = tid & 127, half = tid >> 7;
    if (j < DIM) {
        u64 q0 = wbits[j*4+0], q1 = wbits[j*4+1], y0 = wbits[j*4+2], y1 = wbits[j*4+3];
        bool hasY = (y0 | y1) != 0;
        u32 S = 0, S2 = 0;
        int r0 = half * 64;
        for (int r = r0; r < r0 + 64; ++r) {
            u64 z0 = lb[r][2], z1 = lb[r][3];
            u32 hq = hq_from_bits(lb[r][0], lb[r][1], z0, z1,
                                  q0, q1, y0, y1, hasY, (z0 | z1) != 0);
            S += hq; S2 += hq * hq;
        }
        int pidx = j * NPART + blockIdx.x * 2 + half;
        hS[pidx] = S; hS2[pidx] = S2;
    }
}

// R1: reduce integer h-stats -> fold BN2 into  z = fma(hq, c1q, c0)
__global__ __launch_bounds__(256) void r1_hreduce(
        const u32* __restrict__ hS, const u32* __restrict__ hS2,
        const float* __restrict__ g2, const float* __restrict__ b2,
        float* __restrict__ bn2c) {
    int j = blockIdx.x, tid = threadIdx.x;
    u32 s = 0; u64 s2 = 0;
    for (int k = tid; k < NPART; k += 256) { s += hS[j*NPART+k]; s2 += (u64)hS2[j*NPART+k]; }
    for (int off = 32; off; off >>= 1) { s += __shfl_down(s, off, 64); s2 += __shfl_down(s2, off, 64); }
    __shared__ u32 as_[4]; __shared__ u64 as2_[4];
    int lane = tid & 63, wave = tid >> 6;
    if (lane == 0) { as_[wave] = s; as2_[wave] = s2; }
    __syncthreads();
    if (tid == 0) {
        u32 S = as_[0] + as_[1] + as_[2] + as_[3];
        u64 S2 = as2_[0] + as2_[1] + as2_[2] + as2_[3];
        double m2 = (double)S * 0.25 / (double)BATCH;
        double e2 = (double)S2 * 0.0625 / (double)BATCH;
        double v2 = e2 - m2 * m2;
        float rs = (float)(1.0 / sqrt(v2 + 1e-5));
        float c1 = rs * g2[j];
        float c0 = fmaf(-(float)m2, c1, b2[j]);
        bn2c[j]       = c1 * 0.25f;   // pre-scaled for hq (=4h)
        bn2c[128 + j] = c0;
    }
}

// K2: stage bits in LDS, recompute hq, softsign stats (dual f32 accumulators)
__global__ __launch_bounds__(256) void k2_sstats(
        const u64* __restrict__ xbits, const u64* __restrict__ wbits,
        const float* __restrict__ bn2c,
        float* __restrict__ sS, float* __restrict__ sS2) {
    __shared__ u64 lb[128][4];
    int tid = threadIdx.x;
    ((ulonglong2*)&lb[0][0])[tid] =
        ((const ulonglong2*)(xbits + (size_t)blockIdx.x * 512))[tid];
    __syncthreads();
    int j = tid & 127, half = tid >> 7;
    if (j >= DIM) return;
    u64 q0 = wbits[j*4+0], q1 = wbits[j*4+1], y0 = wbits[j*4+2], y1 = wbits[j*4+3];
    bool hasY = (y0 | y1) != 0;
    float c1q = bn2c[j], c0 = bn2c[128 + j];
    float SsA = 0.f, Ss2A = 0.f, SsB = 0.f, Ss2B = 0.f;
    int r0 = half * 64;
    for (int r = r0; r < r0 + 64; r += 2) {
        u64 z0 = lb[r][2], z1 = lb[r][3];
        u32 hqa = hq_from_bits(lb[r][0], lb[r][1], z0, z1,
                               q0, q1, y0, y1, hasY, (z0 | z1) != 0);
        u64 w0 = lb[r+1][2], w1 = lb[r+1][3];
        u32 hqb = hq_from_bits(lb[r+1][0], lb[r+1][1], w0, w1,
                               q0, q1, y0, y1, hasY, (w0 | w1) != 0);
        float za = fmaf((float)hqa, c1q, c0);
        float sa = za * __builtin_amdgcn_rcpf(1.f + fabsf(za));
        SsA += sa; Ss2A = fmaf(sa, sa, Ss2A);
        float zb = fmaf((float)hqb, c1q, c0);
        float sb = zb * __builtin_amdgcn_rcpf(1.f + fabsf(zb));
        SsB += sb; Ss2B = fmaf(sb, sb, Ss2B);
    }
    int pidx = j * NPART + blockIdx.x * 2 + half;
    sS[pidx] = SsA + SsB; sS2[pidx] = Ss2A + Ss2B;
}

// R2: reduce softsign stats (f64), fold BN1, derive the two integer
// thresholds per column (h1(hq) monotone in hq), pack meta words:
//   meta[2j]   = A | B<<9 | dec<<18     (hq units, A,B <= 482)
//   meta[2j+1] = lw0 | lw1<<16          (2*binarize of lin_w)
__global__ __launch_bounds__(256) void r2_sreduce(
        const float* __restrict__ sS, const float* __restrict__ sS2,
        const float* __restrict__ g1, const float* __restrict__ b1,
        const float* __restrict__ bn2c, const u32* __restrict__ lwq,
        u32* __restrict__ meta) {
    int j = blockIdx.x, tid = threadIdx.x;
    double s = 0.0, s2 = 0.0;
    for (int k = tid; k < NPART; k += 256) { s += (double)sS[j*NPART+k]; s2 += (double)sS2[j*NPART+k]; }
    for (int off = 32; off; off >>= 1) { s += __shfl_down(s, off, 64); s2 += __shfl_down(s2, off, 64); }
    __shared__ double ds_[4], ds2_[4];
    __shared__ float sd1, sd0;
    __shared__ u32 cnt[3];
    __shared__ u32 sfirst, slast;
    int lane = tid & 63, wave = tid >> 6;
    if (lane == 0) { ds_[wave] = s; ds2_[wave] = s2; }
    if (tid < 3) cnt[tid] = 0;
    __syncthreads();
    if (tid == 0) {
        double S = ds_[0] + ds_[1] + ds_[2] + ds_[3];
        double S2 = ds2_[0] + ds2_[1] + ds2_[2] + ds2_[3];
        double m1 = S / (double)BATCH;
        double v1 = S2 / (double)BATCH - m1 * m1;
        float rs = (float)(1.0 / sqrt(v1 + 1e-5));
        float d1 = rs * g1[j];
        float d0 = fmaf(-(float)m1, d1, b1[j]);
        sd1 = d1; sd0 = d0;
    }
    __syncthreads();
    float c1q = bn2c[j], c0 = bn2c[128 + j];
    float d1 = sd1, d0 = sd0;
    for (int hq = tid; hq < 481; hq += 256) {
        float z = fmaf((float)hq, c1q, c0);
        float sv = z * __builtin_amdgcn_rcpf(1.f + fabsf(z));
        float h1 = fmaf(sv, d1, d0);
        u32 hb2 = h1 > 0.f ? 2u : (h1 == 0.f ? 1u : 0u);
        atomicAdd(&cnt[hb2], 1u);
        if (hq == 0)   sfirst = hb2;
        if (hq == 480) slast  = hb2;
    }
    __syncthreads();
    if (tid == 0) {
        u32 n0 = cnt[0], n1 = cnt[1], n2 = cnt[2];
        u32 dec = (slast < sfirst) ? 1u : 0u;
        u32 A = dec ? n2 : n0;
        u32 B = A + n1;
        meta[2*j]   = A | (B << 9) | (dec << 18);
        meta[2*j+1] = lwq[j];
    }
}

__device__ __forceinline__ void proc_col(u64 p0, u64 p1, u64 q0, u64 q1,
                                         u64 mw, u32& oq) {
    u32 hq = ((u32)(__popcll(p0 & q0) + __popcll(p1 & q1))) << 2;
    u32 m  = (u32)mw;
    u32 lw = (u32)(mw >> 32);
    u32 ge = (u32)(hq >= (m & 511u)) + (u32)(hq >= ((m >> 9) & 511u));
    u32 hb2 = (m & (1u << 18)) ? 2u - ge : ge;
    oq += hb2 * lw;            // low16: class0, high16: class1
}

// K3: thread <-> row, chunked-register column loop. NO GLOBAL ATOMICS:
// each block stores its 4 reduced stat partials to distinct addresses
// (oP[block][4]); r3 reduces them. (Atomics onto 2 shared cache lines were
// serializing ~60us across the grid — the real k3 bottleneck, rounds 1-6.)
__global__ __launch_bounds__(256) void k3_out(
        const u64* __restrict__ xbits, const u64* __restrict__ wbits,
        const u32* __restrict__ meta, const u32* __restrict__ oacc,
        u32* __restrict__ oqbuf, u32* __restrict__ oP) {
    __shared__ u64 sq0[DIM], sq1[DIM], smw[DIM], sy0[DIM], sy1[DIM];
    int tid = threadIdx.x;
    for (int k = tid; k < DIM; k += 256) {
        sq0[k] = wbits[k*4+0]; sq1[k] = wbits[k*4+1];
        sy0[k] = wbits[k*4+2]; sy1[k] = wbits[k*4+3];
        smw[k] = (u64)meta[2*k] | ((u64)meta[2*k+1] << 32);
    }
    __syncthreads();
    size_t row = (size_t)blockIdx.x * 256 + tid;
    const ulonglong2* xb = (const ulonglong2*)xbits;
    ulonglong2 rp = xb[row*2], rz = xb[row*2+1];
    u64 p0 = rp.x, p1 = rp.y, z0 = rz.x, z1 = rz.y;
    u32 oq = 0;
    for (int c = 0; c < DIM; c += CH) {
        ulonglong2 A[CH/2], B[CH/2], M[CH/2];
        #pragma unroll
        for (int t = 0; t < CH/2; ++t) {
            A[t] = *(const ulonglong2*)&sq0[c + 2*t];
            B[t] = *(const ulonglong2*)&sq1[c + 2*t];
            M[t] = *(const ulonglong2*)&smw[c + 2*t];
        }
        #pragma unroll
        for (int t = 0; t < CH/2; ++t) {
            proc_col(p0, p1, A[t].x, B[t].x, M[t].x, oq);
            proc_col(p0, p1, A[t].y, B[t].y, M[t].y, oq);
        }
    }
    bool slow = (oacc[8] != 0) | ((z0 | z1) != 0);
    if (__any(slow)) {
        if (slow) {          // exact full recompute (expected ~2 rows/batch)
            oq = 0;
            for (int j = 0; j < DIM; ++j) {
                u64 y0 = sy0[j], y1 = sy1[j];
                u32 hq = hq_from_bits(p0, p1, z0, z1, sq0[j], sq1[j], y0, y1,
                                      (y0 | y1) != 0, (z0 | z1) != 0);
                u64 mw = smw[j];
                u32 m = (u32)mw, lw = (u32)(mw >> 32);
                u32 ge = (u32)(hq >= (m & 511u)) + (u32)(hq >= ((m >> 9) & 511u));
                oq += ((m & (1u << 18)) ? 2u - ge : ge) * lw;
            }
        }
    }
    oqbuf[row] = oq;
    u32 o0 = oq & 0xffffu, o1 = oq >> 16;
    u32 a = o0, b = o1, c2 = o0 * o0, d2 = o1 * o1;
    for (int off = 32; off; off >>= 1) {
        a += __shfl_down(a, off, 64);  b += __shfl_down(b, off, 64);
        c2 += __shfl_down(c2, off, 64); d2 += __shfl_down(d2, off, 64);
    }
    __shared__ u32 r0_[4], r1_[4], r2_[4], r3_[4];
    int lane = tid & 63, wv = tid >> 6;
    if (lane == 0) { r0_[wv] = a; r1_[wv] = b; r2_[wv] = c2; r3_[wv] = d2; }
    __syncthreads();
    if (tid == 0) {
        u32* dst = oP + (size_t)blockIdx.x * 4;
        dst[0] = r0_[0] + r0_[1] + r0_[2] + r0_[3];
        dst[1] = r1_[0] + r1_[1] + r1_[2] + r1_[3];
        dst[2] = r2_[0] + r2_[1] + r2_[2] + r2_[3];
        dst[3] = r3_[0] + r3_[1] + r3_[2] + r3_[3];
    }
}

// R3: reduce the NBLK3 block partials (exact integers) -> fin constants.
__global__ __launch_bounds__(256) void r3_ostats(
        const u32* __restrict__ oP, float* __restrict__ fin) {
    int tid = threadIdx.x;
    u64 a = 0, b = 0, c2 = 0, d2 = 0;
    for (int k = tid; k < NBLK3; k += 256) {
        const u32* p = oP + (size_t)k * 4;
        a += p[0]; b += p[1]; c2 += p[2]; d2 += p[3];
    }
    for (int off = 32; off; off >>= 1) {
        a += __shfl_down(a, off, 64);  b += __shfl_down(b, off, 64);
        c2 += __shfl_down(c2, off, 64); d2 += __shfl_down(d2, off, 64);
    }
    __shared__ u64 s0_[4], s1_[4], s2_[4], s3_[4];
    int lane = tid & 63, wv = tid >> 6;
    if (lane == 0) { s0_[wv] = a; s1_[wv] = b; s2_[wv] = c2; s3_[wv] = d2; }
    __syncthreads();
    if (tid == 0) {
        u64 S[2]  = { s0_[0]+s0_[1]+s0_[2]+s0_[3], s1_[0]+s1_[1]+s1_[2]+s1_[3] };
        u64 S2[2] = { s2_[0]+s2_[1]+s2_[2]+s2_[3], s3_[0]+s3_[1]+s3_[2]+s3_[3] };
        for (int c = 0; c < 2; ++c) {
            double av = (double)S[c] * 0.25 / (double)BATCH;
            double e2 = (double)S2[c] * 0.0625 / (double)BATCH;
            double vo = e2 - av * av;
            fin[c]     = (float)av;
            fin[2 + c] = (float)(1.0 / sqrt(vo + 1e-5));
        }
    }
}

// K4: normalize + 2-class log_softmax (lin_b cancels through no-affine BN).
__global__ __launch_bounds__(256) void k4_final(
        const u32* __restrict__ oqbuf, const float* __restrict__ fin,
        float* __restrict__ out) {
    __shared__ float sfin[4];
    int tid = threadIdx.x;
    if (tid < 4) sfin[tid] = fin[tid];
    __syncthreads();
    size_t row = (size_t)blockIdx.x * 256 + tid;
    u32 v = oqbuf[row];
    float o0 = ((float)(v & 0xffffu) * 0.25f - sfin[0]) * sfin[2];
    float o1 = ((float)(v >> 16)     * 0.25f - sfin[1]) * sfin[3];
    float m = fmaxf(o0, o1);
    float l0 = o0 - m, l1 = o1 - m;
    float ls = logf(expf(l0) + expf(l1));
    ((float2*)out)[row] = make_float2(l0 - ls, l1 - ls);
}

extern "C" void kernel_launch(void* const* d_in, const int* in_sizes, int n_in,
                              void* d_out, int out_size, void* d_ws, size_t ws_size,
                              hipStream_t stream) {
    const float* x  = (const float*)d_in[0];
    const float* cw = (const float*)d_in[1];
    const float* g2 = (const float*)d_in[2];
    const float* b2 = (const float*)d_in[3];
    const float* g1 = (const float*)d_in[4];
    const float* b1 = (const float*)d_in[5];
    const float* lw = (const float*)d_in[6];
    // d_in[7] (lin_b) cancels through the final no-affine batchnorm
    float* out = (float*)d_out;
    if (ws_size < (size_t)WS_TOTAL) return;   // fail loudly via poisoned d_out

    char* ws = (char*)d_ws;
    u64* xbits = (u64*)(ws + WS_XBITS);
    u64* wbits = (u64*)(ws + WS_WBITS);
    u32* lwq   = (u32*)(ws + WS_LWQ);
    u32* meta  = (u32*)(ws + WS_META);
    u32* hS    = (u32*)(ws + WS_HS);
    u32* hS2   = (u32*)(ws + WS_HS2);
    float* sS  = (float*)(ws + WS_SS);
    float* sS2 = (float*)(ws + WS_SS2);
    float* bn2c = (float*)(ws + WS_BN2C);
    u32* oqbuf = (u32*)(ws + WS_OQ);
    u32* oacc  = (u32*)(ws + WS_OACC);
    u32* oP    = (u32*)(ws + WS_OP);
    float* fin = (float*)(ws + WS_FIN);

    kw_pack       <<<1, 256, 0, stream>>>(cw, lw, wbits, lwq, oacc);
    k1_pack_hstats<<<NBLK1, 256, 0, stream>>>(x, wbits, xbits, hS, hS2);
    r1_hreduce    <<<DIM, 256, 0, stream>>>(hS, hS2, g2, b2, bn2c);
    k2_sstats     <<<NBLK1, 256, 0, stream>>>(xbits, wbits, bn2c, sS, sS2);
    r2_sreduce    <<<DIM, 256, 0, stream>>>(sS, sS2, g1, b1, bn2c, lwq, meta);
    k3_out        <<<NBLK3, 256, 0, stream>>>(xbits, wbits, meta, oacc, oqbuf, oP);
    r3_ostats     <<<1, 256, 0, stream>>>(oP, fin);
    k4_final      <<<BATCH/256, 256, 0, stream>>>(oqbuf, fin, out);
}

// Round 8
// 110.222 us; speedup vs baseline: 1.8822x; 1.0481x over previous
//
#include <hip/hip_runtime.h>
#include <stdint.h>
#include <math.h>

typedef unsigned long long u64;
typedef uint32_t u32;

#define BATCH   262144
#define DIM     120
#define NBLK1   2048      // K1/K2: 128 rows per block
#define NPART   4096      // partial slots per column (2 halves * 2048 blocks)
#define CH      8         // k3: columns per register chunk
#define NBLK3   1024      // k3 blocks (256 rows each)

// Bit permutation (x and w MUST match): element c -> plane (c&3), bit (c>>2).
// Row words: p0 = plane0 | plane1<<30 ; p1 = plane2 | plane3<<30 (60 bits used).

// ---------------- workspace layout (bytes) ----------------
#define WS_XBITS   0              // u64[BATCH*4]            8,388,608
#define WS_WBITS   8388608        // u64[128*4]                  4,096
#define WS_LWQ     8392704        // u32[128]                      512
#define WS_META    8393216        // u32[256] (2 per col)        1,024
#define WS_HS      8394240        // u32[120*4096]           1,966,080
#define WS_HS2     10360320      // u32[120*4096]           1,966,080
#define WS_SS      12326400      // f32[120*4096]           1,966,080
#define WS_SS2     14292480      // f32[120*4096]           1,966,080
#define WS_BN2C    16258560      // f32[256]  (c1q[j], c0[128+j])
#define WS_OQ      16259584      // u32[BATCH]              1,048,576
#define WS_OACC    17308160      // u32 yflag@32 (slots 0..31 legacy)
#define WS_OP      17308224      // u32[NBLK3*4] block partials    16,384
#define WS_TOTAL   17324624

// Pack conv_w via float4 2-rows-per-wave ballots in the permuted bit order.
// Zero pad columns, pack lin_w binarize, set yflag if any conv_w == 0.0.
__global__ __launch_bounds__(256) void kw_pack(
        const float* __restrict__ w, const float* __restrict__ lw,
        u64* __restrict__ wbits, u32* __restrict__ lwq, u32* __restrict__ oaccz) {
    int tid = threadIdx.x, lane = tid & 63, wv = tid >> 6;
    int l = lane & 31, h = lane >> 5;
    if (tid < 12) oaccz[tid] = 0;      // incl. yflag @ word 8
    __syncthreads();
    u64 accy = 0;
    const u64 M = 0x3FFFFFFFull;
    for (int jj = wv * 2; jj < DIM; jj += 8) {
        int j = jj + h;
        float4 v = make_float4(-1.f, -1.f, -1.f, -1.f);
        if (l < 30) v = *(const float4*)(w + (size_t)j * DIM + l * 4);
        u64 m0 = __ballot(v.x > 0.f), m1 = __ballot(v.y > 0.f);
        u64 m2 = __ballot(v.z > 0.f), m3 = __ballot(v.w > 0.f);
        u64 n0 = __ballot(v.x == 0.f), n1 = __ballot(v.y == 0.f);
        u64 n2 = __ballot(v.z == 0.f), n3 = __ballot(v.w == 0.f);
        accy |= (n0 | n1 | n2 | n3);
        if (l == 0) {
            u32 sh = h ? 32 : 0;
            wbits[j*4+0] = ((m0>>sh)&M) | (((m1>>sh)&M) << 30);
            wbits[j*4+1] = ((m2>>sh)&M) | (((m3>>sh)&M) << 30);
            wbits[j*4+2] = ((n0>>sh)&M) | (((n1>>sh)&M) << 30);
            wbits[j*4+3] = ((n2>>sh)&M) | (((n3>>sh)&M) << 30);
        }
    }
    if (lane == 0 && accy) atomicOr(&oaccz[8], 1u);
    if (tid >= 120 && tid < 128) {        // zero pad columns
        wbits[tid*4+0] = 0; wbits[tid*4+1] = 0;
        wbits[tid*4+2] = 0; wbits[tid*4+3] = 0;
    }
    if (tid < DIM) {
        float w0 = lw[tid], w1 = lw[DIM + tid];
        u32 l0 = w0 > 0.f ? 2u : (w0 == 0.f ? 1u : 0u);
        u32 l1 = w1 > 0.f ? 2u : (w1 == 0.f ? 1u : 0u);
        lwq[tid] = l0 | (l1 << 16);
    }
}

__device__ __forceinline__ u32 hq_from_bits(u64 p0, u64 p1, u64 z0, u64 z1,
                                            u64 q0, u64 q1, u64 y0, u64 y1,
                                            bool hasY, bool hasZ) {
    u32 hq = (u32)(__popcll(p0 & q0) + __popcll(p1 & q1)) << 2;
    if (hasY)
        hq += 2u * (u32)(__popcll(p0 & y0) + __popcll(p1 & y1))
            + (u32)(__popcll(z0 & y0) + __popcll(z1 & y1));
    if (hasZ)
        hq += 2u * (u32)(__popcll(z0 & q0) + __popcll(z1 & q1));
    return hq;   // == 4 * h, exact integer in [0, 480]
}

// K1: pack x (float4, 2 rows per wave-iteration -> 16 iters), store bits,
// then per-column integer sums of hq and hq^2 (exact, deterministic).
__global__ __launch_bounds__(256) void k1_pack_hstats(
        const float* __restrict__ x, const u64* __restrict__ wbits,
        u64* __restrict__ xbits, u32* __restrict__ hS, u32* __restrict__ hS2) {
    __shared__ u64 lb[128][4];
    int tid = threadIdx.x, lane = tid & 63, wave = tid >> 6;
    int l = lane & 31, h = lane >> 5;
    size_t rowbase = (size_t)blockIdx.x * 128;
    const u64 M = 0x3FFFFFFFull;

    for (int rr = 0; rr < 16; ++rr) {
        int r = rr * 8 + wave * 2 + h;
        float4 v = make_float4(-1.f, -1.f, -1.f, -1.f);
        if (l < 30) v = *(const float4*)(x + (rowbase + r) * (size_t)DIM + l * 4);
        u64 m0 = __ballot(v.x > 0.f), m1 = __ballot(v.y > 0.f);
        u64 m2 = __ballot(v.z > 0.f), m3 = __ballot(v.w > 0.f);
        u64 n0 = __ballot(v.x == 0.f), n1 = __ballot(v.y == 0.f);
        u64 n2 = __ballot(v.z == 0.f), n3 = __ballot(v.w == 0.f);
        if (l == 0) {
            u32 sh = h ? 32 : 0;
            lb[r][0] = ((m0>>sh)&M) | (((m1>>sh)&M) << 30);
            lb[r][1] = ((m2>>sh)&M) | (((m3>>sh)&M) << 30);
            lb[r][2] = ((n0>>sh)&M) | (((n1>>sh)&M) << 30);
            lb[r][3] = ((n2>>sh)&M) | (((n3>>sh)&M) << 30);
        }
    }
    __syncthreads();
    ((ulonglong2*)(xbits + (size_t)blockIdx.x * 512))[tid] =
        ((const ulonglong2*)&lb[0][0])[tid];

    int j = tid & 127, half = tid >> 7;
    if (j < DIM) {
        u64 q0 = wbits[j*4+0], q1 = wbits[j*4+1], y0 = wbits[j*4+2], y1 = wbits[j*4+3];
        bool hasY = (y0 | y1) != 0;
        u32 S = 0, S2 = 0;
        int r0 = half * 64;
        for (int r = r0; r < r0 + 64; ++r) {
            u64 z0 = lb[r][2], z1 = lb[r][3];
            u32 hq = hq_from_bits(lb[r][0], lb[r][1], z0, z1,
                                  q0, q1, y0, y1, hasY, (z0 | z1) != 0);
            S += hq; S2 += hq * hq;
        }
        int pidx = j * NPART + blockIdx.x * 2 + half;
        hS[pidx] = S; hS2[pidx] = S2;
    }
}

// R1: reduce integer h-stats -> fold BN2 into  z = fma(hq, c1q, c0)
__global__ __launch_bounds__(256) void r1_hreduce(
        const u32* __restrict__ hS, const u32* __restrict__ hS2,
        const float* __restrict__ g2, const float* __restrict__ b2,
        float* __restrict__ bn2c) {
    int j = blockIdx.x, tid = threadIdx.x;
    u32 s = 0; u64 s2 = 0;
    for (int k = tid; k < NPART; k += 256) { s += hS[j*NPART+k]; s2 += (u64)hS2[j*NPART+k]; }
    for (int off = 32; off; off >>= 1) { s += __shfl_down(s, off, 64); s2 += __shfl_down(s2, off, 64); }
    __shared__ u32 as_[4]; __shared__ u64 as2_[4];
    int lane = tid & 63, wave = tid >> 6;
    if (lane == 0) { as_[wave] = s; as2_[wave] = s2; }
    __syncthreads();
    if (tid == 0) {
        u32 S = as_[0] + as_[1] + as_[2] + as_[3];
        u64 S2 = as2_[0] + as2_[1] + as2_[2] + as2_[3];
        double m2 = (double)S * 0.25 / (double)BATCH;
        double e2 = (double)S2 * 0.0625 / (double)BATCH;
        double v2 = e2 - m2 * m2;
        float rs = (float)(1.0 / sqrt(v2 + 1e-5));
        float c1 = rs * g2[j];
        float c0 = fmaf(-(float)m2, c1, b2[j]);
        bn2c[j]       = c1 * 0.25f;   // pre-scaled for hq (=4h)
        bn2c[128 + j] = c0;
    }
}

// K2: stage bits in LDS, recompute hq, softsign stats (dual f32 accumulators)
__global__ __launch_bounds__(256) void k2_sstats(
        const u64* __restrict__ xbits, const u64* __restrict__ wbits,
        const float* __restrict__ bn2c,
        float* __restrict__ sS, float* __restrict__ sS2) {
    __shared__ u64 lb[128][4];
    int tid = threadIdx.x;
    ((ulonglong2*)&lb[0][0])[tid] =
        ((const ulonglong2*)(xbits + (size_t)blockIdx.x * 512))[tid];
    __syncthreads();
    int j = tid & 127, half = tid >> 7;
    if (j >= DIM) return;
    u64 q0 = wbits[j*4+0], q1 = wbits[j*4+1], y0 = wbits[j*4+2], y1 = wbits[j*4+3];
    bool hasY = (y0 | y1) != 0;
    float c1q = bn2c[j], c0 = bn2c[128 + j];
    float SsA = 0.f, Ss2A = 0.f, SsB = 0.f, Ss2B = 0.f;
    int r0 = half * 64;
    for (int r = r0; r < r0 + 64; r += 2) {
        u64 z0 = lb[r][2], z1 = lb[r][3];
        u32 hqa = hq_from_bits(lb[r][0], lb[r][1], z0, z1,
                               q0, q1, y0, y1, hasY, (z0 | z1) != 0);
        u64 w0 = lb[r+1][2], w1 = lb[r+1][3];
        u32 hqb = hq_from_bits(lb[r+1][0], lb[r+1][1], w0, w1,
                               q0, q1, y0, y1, hasY, (w0 | w1) != 0);
        float za = fmaf((float)hqa, c1q, c0);
        float sa = za * __builtin_amdgcn_rcpf(1.f + fabsf(za));
        SsA += sa; Ss2A = fmaf(sa, sa, Ss2A);
        float zb = fmaf((float)hqb, c1q, c0);
        float sb = zb * __builtin_amdgcn_rcpf(1.f + fabsf(zb));
        SsB += sb; Ss2B = fmaf(sb, sb, Ss2B);
    }
    int pidx = j * NPART + blockIdx.x * 2 + half;
    sS[pidx] = SsA + SsB; sS2[pidx] = Ss2A + Ss2B;
}

// R2: reduce softsign stats (f64), fold BN1, derive the two integer
// thresholds per column (h1(hq) monotone in hq), pack meta words:
//   meta[2j]   = A | B<<9 | dec<<18     (hq units, A,B <= 482)
//   meta[2j+1] = lw0 | lw1<<16          (2*binarize of lin_w)
__global__ __launch_bounds__(256) void r2_sreduce(
        const float* __restrict__ sS, const float* __restrict__ sS2,
        const float* __restrict__ g1, const float* __restrict__ b1,
        const float* __restrict__ bn2c, const u32* __restrict__ lwq,
        u32* __restrict__ meta) {
    int j = blockIdx.x, tid = threadIdx.x;
    double s = 0.0, s2 = 0.0;
    for (int k = tid; k < NPART; k += 256) { s += (double)sS[j*NPART+k]; s2 += (double)sS2[j*NPART+k]; }
    for (int off = 32; off; off >>= 1) { s += __shfl_down(s, off, 64); s2 += __shfl_down(s2, off, 64); }
    __shared__ double ds_[4], ds2_[4];
    __shared__ float sd1, sd0;
    __shared__ u32 cnt[3];
    __shared__ u32 sfirst, slast;
    int lane = tid & 63, wave = tid >> 6;
    if (lane == 0) { ds_[wave] = s; ds2_[wave] = s2; }
    if (tid < 3) cnt[tid] = 0;
    __syncthreads();
    if (tid == 0) {
        double S = ds_[0] + ds_[1] + ds_[2] + ds_[3];
        double S2 = ds2_[0] + ds2_[1] + ds2_[2] + ds2_[3];
        double m1 = S / (double)BATCH;
        double v1 = S2 / (double)BATCH - m1 * m1;
        float rs = (float)(1.0 / sqrt(v1 + 1e-5));
        float d1 = rs * g1[j];
        float d0 = fmaf(-(float)m1, d1, b1[j]);
        sd1 = d1; sd0 = d0;
    }
    __syncthreads();
    float c1q = bn2c[j], c0 = bn2c[128 + j];
    float d1 = sd1, d0 = sd0;
    for (int hq = tid; hq < 481; hq += 256) {
        float z = fmaf((float)hq, c1q, c0);
        float sv = z * __builtin_amdgcn_rcpf(1.f + fabsf(z));
        float h1 = fmaf(sv, d1, d0);
        u32 hb2 = h1 > 0.f ? 2u : (h1 == 0.f ? 1u : 0u);
        atomicAdd(&cnt[hb2], 1u);
        if (hq == 0)   sfirst = hb2;
        if (hq == 480) slast  = hb2;
    }
    __syncthreads();
    if (tid == 0) {
        u32 n0 = cnt[0], n1 = cnt[1], n2 = cnt[2];
        u32 dec = (slast < sfirst) ? 1u : 0u;
        u32 A = dec ? n2 : n0;
        u32 B = A + n1;
        meta[2*j]   = A | (B << 9) | (dec << 18);
        meta[2*j+1] = lwq[j];
    }
}

__device__ __forceinline__ void proc_col(u64 p0, u64 p1, u64 q0, u64 q1,
                                         u64 mw, u32& oq) {
    u32 hq = ((u32)(__popcll(p0 & q0) + __popcll(p1 & q1))) << 2;
    u32 m  = (u32)mw;
    u32 lw = (u32)(mw >> 32);
    u32 ge = (u32)(hq >= (m & 511u)) + (u32)(hq >= ((m >> 9) & 511u));
    u32 hb2 = (m & (1u << 18)) ? 2u - ge : ge;
    oq += hb2 * lw;            // low16: class0, high16: class1
}

// K3: thread <-> row, chunked-register column loop, per-block stat partials
// to distinct addresses (no global atomics — the round-1..6 serializer).
__global__ __launch_bounds__(256) void k3_out(
        const u64* __restrict__ xbits, const u64* __restrict__ wbits,
        const u32* __restrict__ meta, const u32* __restrict__ oacc,
        u32* __restrict__ oqbuf, u32* __restrict__ oP) {
    __shared__ u64 sq0[DIM], sq1[DIM], smw[DIM], sy0[DIM], sy1[DIM];
    int tid = threadIdx.x;
    for (int k = tid; k < DIM; k += 256) {
        sq0[k] = wbits[k*4+0]; sq1[k] = wbits[k*4+1];
        sy0[k] = wbits[k*4+2]; sy1[k] = wbits[k*4+3];
        smw[k] = (u64)meta[2*k] | ((u64)meta[2*k+1] << 32);
    }
    __syncthreads();
    size_t row = (size_t)blockIdx.x * 256 + tid;
    const ulonglong2* xb = (const ulonglong2*)xbits;
    ulonglong2 rp = xb[row*2], rz = xb[row*2+1];
    u64 p0 = rp.x, p1 = rp.y, z0 = rz.x, z1 = rz.y;
    u32 oq = 0;
    for (int c = 0; c < DIM; c += CH) {
        ulonglong2 A[CH/2], B[CH/2], M[CH/2];
        #pragma unroll
        for (int t = 0; t < CH/2; ++t) {
            A[t] = *(const ulonglong2*)&sq0[c + 2*t];
            B[t] = *(const ulonglong2*)&sq1[c + 2*t];
            M[t] = *(const ulonglong2*)&smw[c + 2*t];
        }
        #pragma unroll
        for (int t = 0; t < CH/2; ++t) {
            proc_col(p0, p1, A[t].x, B[t].x, M[t].x, oq);
            proc_col(p0, p1, A[t].y, B[t].y, M[t].y, oq);
        }
    }
    bool slow = (oacc[8] != 0) | ((z0 | z1) != 0);
    if (__any(slow)) {
        if (slow) {          // exact full recompute (expected ~2 rows/batch)
            oq = 0;
            for (int j = 0; j < DIM; ++j) {
                u64 y0 = sy0[j], y1 = sy1[j];
                u32 hq = hq_from_bits(p0, p1, z0, z1, sq0[j], sq1[j], y0, y1,
                                      (y0 | y1) != 0, (z0 | z1) != 0);
                u64 mw = smw[j];
                u32 m = (u32)mw, lw = (u32)(mw >> 32);
                u32 ge = (u32)(hq >= (m & 511u)) + (u32)(hq >= ((m >> 9) & 511u));
                oq += ((m & (1u << 18)) ? 2u - ge : ge) * lw;
            }
        }
    }
    oqbuf[row] = oq;
    u32 o0 = oq & 0xffffu, o1 = oq >> 16;
    u32 a = o0, b = o1, c2 = o0 * o0, d2 = o1 * o1;
    for (int off = 32; off; off >>= 1) {
        a += __shfl_down(a, off, 64);  b += __shfl_down(b, off, 64);
        c2 += __shfl_down(c2, off, 64); d2 += __shfl_down(d2, off, 64);
    }
    __shared__ u32 r0_[4], r1_[4], r2_[4], r3_[4];
    int lane = tid & 63, wv = tid >> 6;
    if (lane == 0) { r0_[wv] = a; r1_[wv] = b; r2_[wv] = c2; r3_[wv] = d2; }
    __syncthreads();
    if (tid == 0) {
        u32* dst = oP + (size_t)blockIdx.x * 4;
        dst[0] = r0_[0] + r0_[1] + r0_[2] + r0_[3];
        dst[1] = r1_[0] + r1_[1] + r1_[2] + r1_[3];
        dst[2] = r2_[0] + r2_[1] + r2_[2] + r2_[3];
        dst[3] = r3_[0] + r3_[1] + r3_[2] + r3_[3];
    }
}

// K4 (r3 fused): each block redundantly reduces the 16KB oP partials to the
// output-BN constants (exact integers, f64 finalize — identical math to the
// old r3), then normalizes its 256 rows + 2-class log_softmax.
__global__ __launch_bounds__(256) void k4_final(
        const u32* __restrict__ oqbuf, const u32* __restrict__ oP,
        float* __restrict__ out) {
    int tid = threadIdx.x;
    u64 a = 0, b = 0, c2 = 0, d2 = 0;
    for (int k = tid; k < NBLK3; k += 256) {
        uint4 p = ((const uint4*)oP)[k];
        a += p.x; b += p.y; c2 += p.z; d2 += p.w;
    }
    for (int off = 32; off; off >>= 1) {
        a += __shfl_down(a, off, 64);  b += __shfl_down(b, off, 64);
        c2 += __shfl_down(c2, off, 64); d2 += __shfl_down(d2, off, 64);
    }
    __shared__ u64 s0_[4], s1_[4], s2_[4], s3_[4];
    __shared__ float sfin[4];
    int lane = tid & 63, wv = tid >> 6;
    if (lane == 0) { s0_[wv] = a; s1_[wv] = b; s2_[wv] = c2; s3_[wv] = d2; }
    __syncthreads();
    if (tid < 2) {
        u64 S  = (tid == 0) ? s0_[0]+s0_[1]+s0_[2]+s0_[3] : s1_[0]+s1_[1]+s1_[2]+s1_[3];
        u64 S2 = (tid == 0) ? s2_[0]+s2_[1]+s2_[2]+s2_[3] : s3_[0]+s3_[1]+s3_[2]+s3_[3];
        double av = (double)S * 0.25 / (double)BATCH;
        double e2 = (double)S2 * 0.0625 / (double)BATCH;
        double vo = e2 - av * av;
        sfin[tid]     = (float)av;
        sfin[2 + tid] = (float)(1.0 / sqrt(vo + 1e-5));
    }
    __syncthreads();
    size_t row = (size_t)blockIdx.x * 256 + tid;
    u32 v = oqbuf[row];
    float o0 = ((float)(v & 0xffffu) * 0.25f - sfin[0]) * sfin[2];
    float o1 = ((float)(v >> 16)     * 0.25f - sfin[1]) * sfin[3];
    float m = fmaxf(o0, o1);
    float l0 = o0 - m, l1 = o1 - m;
    float ls = logf(expf(l0) + expf(l1));
    ((float2*)out)[row] = make_float2(l0 - ls, l1 - ls);
}

extern "C" void kernel_launch(void* const* d_in, const int* in_sizes, int n_in,
                              void* d_out, int out_size, void* d_ws, size_t ws_size,
                              hipStream_t stream) {
    const float* x  = (const float*)d_in[0];
    const float* cw = (const float*)d_in[1];
    const float* g2 = (const float*)d_in[2];
    const float* b2 = (const float*)d_in[3];
    const float* g1 = (const float*)d_in[4];
    const float* b1 = (const float*)d_in[5];
    const float* lw = (const float*)d_in[6];
    // d_in[7] (lin_b) cancels through the final no-affine batchnorm
    float* out = (float*)d_out;
    if (ws_size < (size_t)WS_TOTAL) return;   // fail loudly via poisoned d_out

    char* ws = (char*)d_ws;
    u64* xbits = (u64*)(ws + WS_XBITS);
    u64* wbits = (u64*)(ws + WS_WBITS);
    u32* lwq   = (u32*)(ws + WS_LWQ);
    u32* meta  = (u32*)(ws + WS_META);
    u32* hS    = (u32*)(ws + WS_HS);
    u32* hS2   = (u32*)(ws + WS_HS2);
    float* sS  = (float*)(ws + WS_SS);
    float* sS2 = (float*)(ws + WS_SS2);
    float* bn2c = (float*)(ws + WS_BN2C);
    u32* oqbuf = (u32*)(ws + WS_OQ);
    u32* oacc  = (u32*)(ws + WS_OACC);
    u32* oP    = (u32*)(ws + WS_OP);

    kw_pack       <<<1, 256, 0, stream>>>(cw, lw, wbits, lwq, oacc);
    k1_pack_hstats<<<NBLK1, 256, 0, stream>>>(x, wbits, xbits, hS, hS2);
    r1_hreduce    <<<DIM, 256, 0, stream>>>(hS, hS2, g2, b2, bn2c);
    k2_sstats     <<<NBLK1, 256, 0, stream>>>(xbits, wbits, bn2c, sS, sS2);
    r2_sreduce    <<<DIM, 256, 0, stream>>>(sS, sS2, g1, b1, bn2c, lwq, meta);
    k3_out        <<<NBLK3, 256, 0, stream>>>(xbits, wbits, meta, oacc, oqbuf, oP);
    k4_final      <<<NBLK3, 256, 0, stream>>>(oqbuf, oP, out);
}